// Round 2
// baseline (1315.725 us; speedup 1.0000x reference)
//
#include <hip/hip_runtime.h>

#define H 256
#define KNN 16
#define NPT 256
#define BB 64

// ---------------------------------------------------------------------------
// K1: exact KNN (k=16) per point, stable tie-break (lower index first),
// matching jax.lax.top_k(-dist) semantics. One block per batch, thread=point.
// ---------------------------------------------------------------------------
__global__ __launch_bounds__(NPT) void knn_kernel(const float* __restrict__ centers,
                                                  int* __restrict__ knn) {
    __shared__ float cx[NPT], cy[NPT], cz[NPT], sq[NPT];
    int b = blockIdx.x, n = threadIdx.x;
    const float* cb = centers + (size_t)b * NPT * 3;
    float x = cb[n * 3 + 0], y = cb[n * 3 + 1], z = cb[n * 3 + 2];
    cx[n] = x; cy[n] = y; cz[n] = z;
    sq[n] = x * x + y * y + z * z;
    __syncthreads();
    float bd[KNN];
    int bi[KNN];
#pragma unroll
    for (int j = 0; j < KNN; j++) { bd[j] = 1e30f; bi[j] = 0; }
    float sn = sq[n];
    for (int m = 0; m < NPT; m++) {
        float dot = x * cx[m] + y * cy[m] + z * cz[m];
        float d2 = (sn + sq[m]) - 2.0f * dot;
        float d = sqrtf(fmaxf(d2, 0.0f));
        if (d < bd[KNN - 1]) {  // strict: equal-dist later index stays out
            bd[KNN - 1] = d; bi[KNN - 1] = m;
#pragma unroll
            for (int p = KNN - 1; p > 0; --p) {
                if (bd[p - 1] > bd[p]) {  // strict: stable among equals
                    float td = bd[p - 1]; bd[p - 1] = bd[p]; bd[p] = td;
                    int ti = bi[p - 1]; bi[p - 1] = bi[p]; bi[p] = ti;
                }
            }
        }
    }
    int* kp = knn + (b * NPT + n) * KNN;
#pragma unroll
    for (int j = 0; j < KNN; j++) kp[j] = bi[j];
}

// ---------------------------------------------------------------------------
// K2: text gate / bias per batch: gate = sigmoid(t@Wg+bg), tbias = t@Wt+bt
// ---------------------------------------------------------------------------
__global__ __launch_bounds__(H) void gate_kernel(const float* __restrict__ tg_g,
                                                 const float* __restrict__ wg,
                                                 const float* __restrict__ bg,
                                                 const float* __restrict__ wtb,
                                                 const float* __restrict__ btb,
                                                 float* __restrict__ gate,
                                                 float* __restrict__ tbias) {
    __shared__ float tg[H];
    int b = blockIdx.x, h = threadIdx.x;
    tg[h] = tg_g[b * H + h];
    __syncthreads();
    float ag = bg[h], ab = btb[h];
    for (int i = 0; i < H; i++) {
        float t = tg[i];
        ag += t * wg[i * H + h];
        ab += t * wtb[i * H + h];
    }
    gate[b * H + h] = 1.0f / (1.0f + expf(-ag));
    tbias[b * H + h] = ab;
}

// ---------------------------------------------------------------------------
// K3: MSG[bn,h] = relu(feat[bn]@Wm + bm)  (computed per point, not per edge)
// 8 points per block.
// ---------------------------------------------------------------------------
__global__ __launch_bounds__(H) void msg_kernel(const float* __restrict__ feat,
                                                const float* __restrict__ wm,
                                                const float* __restrict__ bm,
                                                float* __restrict__ MSG) {
    __shared__ float fr[H * 8];  // [i][r]
    int p0 = blockIdx.x * 8;
    int t = threadIdx.x;
#pragma unroll
    for (int r = 0; r < 8; r++) fr[t * 8 + r] = feat[((size_t)(p0 + r)) * H + t];
    __syncthreads();
    float acc[8];
    float bmh = bm[t];
#pragma unroll
    for (int r = 0; r < 8; r++) acc[r] = bmh;
    for (int i = 0; i < H; i++) {
        float w = wm[i * H + t];
        const float4* fp = (const float4*)&fr[i * 8];
        float4 a0 = fp[0], a1 = fp[1];
        acc[0] += a0.x * w; acc[1] += a0.y * w; acc[2] += a0.z * w; acc[3] += a0.w * w;
        acc[4] += a1.x * w; acc[5] += a1.y * w; acc[6] += a1.z * w; acc[7] += a1.w * w;
    }
#pragma unroll
    for (int r = 0; r < 8; r++)
        MSG[((size_t)(p0 + r)) * H + t] = fmaxf(acc[r], 0.0f);
}

// ---------------------------------------------------------------------------
// K4: fused edge pipeline, one block per point (b,n), 256 threads.
// ---------------------------------------------------------------------------
__global__ __launch_bounds__(H) void edge_kernel(
    const float* __restrict__ feat, const float* __restrict__ centers,
    const float* __restrict__ w1, const float* __restrict__ b1,
    const float* __restrict__ w2, const float* __restrict__ b2,
    const float* __restrict__ we1, const float* __restrict__ be1,
    const float* __restrict__ we2, const float* __restrict__ be2,
    const float* __restrict__ wo, const float* __restrict__ bo,
    const float* __restrict__ gamma, const float* __restrict__ beta,
    const int* __restrict__ knn, const float* __restrict__ gate,
    const float* __restrict__ tbias, const float* __restrict__ MSG,
    float* __restrict__ out) {
    __shared__ float fn[H];           // feat_n
    __shared__ float fnb[KNN][H];     // neighbor feats; reused as e1[16][128]
    __shared__ float g1e[H][20];      // g1 then edge_feat, [i][j], padded to 20
    __shared__ float geomS[KNN][4];
    __shared__ int nidxS[KNN];
    __shared__ float logitsS[KNN];
    __shared__ float alphaS[KNN];
    __shared__ float ctxS[H];
    __shared__ float red[8];

    int bn = blockIdx.x;
    int b = bn >> 8, n = bn & 255;
    int h = threadIdx.x;

    fn[h] = feat[(size_t)bn * H + h];
    if (h < KNN) nidxS[h] = knn[bn * KNN + h];
    __syncthreads();

#pragma unroll
    for (int j = 0; j < KNN; j++) {
        int m = nidxS[j];
        fnb[j][h] = feat[((size_t)b * NPT + m) * H + h];
    }
    if (h < KNN) {
        int m = nidxS[h];
        const float* cb = centers + (size_t)b * NPT * 3;
        float rx = cb[m * 3 + 0] - cb[n * 3 + 0];
        float ry = cb[m * 3 + 1] - cb[n * 3 + 1];
        float rz = cb[m * 3 + 2] - cb[n * 3 + 2];
        float dist = sqrtf(rx * rx + ry * ry + rz * rz) + 1e-6f;
        geomS[h][0] = rx; geomS[h][1] = ry; geomS[h][2] = rz;
        geomS[h][3] = log1pf(dist);
    }
    float gateh = gate[b * H + h];
    float tbh = tbias[b * H + h];
    __syncthreads();

    // g1[i=h][j] = relu(geom[j] @ W1[:,h] + b1[h])
    {
        float w1c0 = w1[0 * H + h], w1c1 = w1[1 * H + h];
        float w1c2 = w1[2 * H + h], w1c3 = w1[3 * H + h];
        float b1h = b1[h];
#pragma unroll
        for (int j = 0; j < KNN; j++) {
            float g = b1h + geomS[j][0] * w1c0 + geomS[j][1] * w1c1 +
                      geomS[j][2] * w1c2 + geomS[j][3] * w1c3;
            g1e[h][j] = fmaxf(g, 0.0f);
        }
    }
    __syncthreads();

    // W2 GEMM: acc[j] = sum_i g1[i][j] * w2[i][h]
    float acc[KNN];
#pragma unroll
    for (int j = 0; j < KNN; j++) acc[j] = 0.0f;
    for (int i = 0; i < H; i++) {
        float w = w2[i * H + h];
        const float4* gp = (const float4*)&g1e[i][0];
        float4 a0 = gp[0], a1 = gp[1], a2 = gp[2], a3 = gp[3];
        acc[0] += a0.x * w; acc[1] += a0.y * w; acc[2] += a0.z * w; acc[3] += a0.w * w;
        acc[4] += a1.x * w; acc[5] += a1.y * w; acc[6] += a1.z * w; acc[7] += a1.w * w;
        acc[8] += a2.x * w; acc[9] += a2.y * w; acc[10] += a2.z * w; acc[11] += a2.w * w;
        acc[12] += a3.x * w; acc[13] += a3.y * w; acc[14] += a3.z * w; acc[15] += a3.w * w;
    }
    __syncthreads();  // all g1 reads done before overwrite with edge_feat

    {
        float b2h = b2[h];
#pragma unroll
        for (int j = 0; j < KNN; j++) {
            float emb = fmaxf(acc[j] + b2h, 0.0f);
            float cond = emb * gateh + tbh;
            g1e[h][j] = tanhf(fn[h] + fnb[j][h] + cond);
        }
    }
    __syncthreads();

    // edge MLP layer1: 2 edge-groups x 128 cols
    int col = h & 127, eg = h >> 7;  // edges eg*8 .. eg*8+7
    float acc2[8];
#pragma unroll
    for (int r = 0; r < 8; r++) acc2[r] = 0.0f;
    for (int i = 0; i < H; i++) {
        float w = we1[i * 128 + col];
        const float4* gp = (const float4*)&g1e[i][eg * 8];
        float4 a0 = gp[0], a1 = gp[1];
        acc2[0] += a0.x * w; acc2[1] += a0.y * w; acc2[2] += a0.z * w; acc2[3] += a0.w * w;
        acc2[4] += a1.x * w; acc2[5] += a1.y * w; acc2[6] += a1.z * w; acc2[7] += a1.w * w;
    }
    __syncthreads();  // fnb (neighbor feats) no longer needed -> reuse as e1
    float* e1 = &fnb[0][0];  // [16][128]
    {
        float be1c = be1[col];
#pragma unroll
        for (int r = 0; r < 8; r++)
            e1[(eg * 8 + r) * 128 + col] = fmaxf(acc2[r] + be1c, 0.0f);
    }
    __syncthreads();

    // logits: thread = j*16 + u
    {
        int j = h >> 4, u = h & 15;
        float p = 0.0f;
#pragma unroll
        for (int q = 0; q < 8; q++) {
            int c = u + q * 16;
            p += e1[j * 128 + c] * we2[c];
        }
        p += __shfl_down(p, 8, 16);
        p += __shfl_down(p, 4, 16);
        p += __shfl_down(p, 2, 16);
        p += __shfl_down(p, 1, 16);
        if (u == 0) logitsS[j] = p + be2[0];
    }
    __syncthreads();
    if (h < KNN) {
        float mx = -1e30f;
#pragma unroll
        for (int j = 0; j < KNN; j++) mx = fmaxf(mx, logitsS[j]);
        float s = 0.0f;
#pragma unroll
        for (int j = 0; j < KNN; j++) s += expf(logitsS[j] - mx);
        alphaS[h] = expf(logitsS[h] - mx) / s;
    }
    __syncthreads();

    // ctx[h] = sum_j alpha[j] * MSG[b, nidx[j], h]
    {
        float c = 0.0f;
#pragma unroll
        for (int j = 0; j < KNN; j++)
            c += alphaS[j] * MSG[((size_t)b * NPT + nidxS[j]) * H + h];
        ctxS[h] = c;
    }
    __syncthreads();

    // out-proj + residual + LayerNorm
    float o = bo[h];
    for (int i = 0; i < H; i++) o += fn[i] * wo[i * H + h];
    for (int i = 0; i < H; i++) o += ctxS[i] * wo[(H + i) * H + h];
    float x = fn[h] + fmaxf(o, 0.0f);

    int wave = h >> 6, lane = h & 63;
    float s = x;
#pragma unroll
    for (int d = 32; d > 0; d >>= 1) s += __shfl_down(s, d);
    if (lane == 0) red[wave] = s;
    __syncthreads();
    float mu = (red[0] + red[1] + red[2] + red[3]) * (1.0f / H);
    float dx = x - mu;
    float s2 = dx * dx;
#pragma unroll
    for (int d = 32; d > 0; d >>= 1) s2 += __shfl_down(s2, d);
    if (lane == 0) red[4 + wave] = s2;
    __syncthreads();
    float var = (red[4] + red[5] + red[6] + red[7]) * (1.0f / H);
    float y = dx * rsqrtf(var + 1e-5f) * gamma[h] + beta[h];
    out[(size_t)bn * H + h] = y;
}

// ---------------------------------------------------------------------------
extern "C" void kernel_launch(void* const* d_in, const int* in_sizes, int n_in,
                              void* d_out, int out_size, void* d_ws, size_t ws_size,
                              hipStream_t stream) {
    const float* feat    = (const float*)d_in[0];
    const float* centers = (const float*)d_in[1];
    const float* textg   = (const float*)d_in[2];
    const float* w1      = (const float*)d_in[3];
    const float* b1      = (const float*)d_in[4];
    const float* w2      = (const float*)d_in[5];
    const float* b2      = (const float*)d_in[6];
    const float* wg      = (const float*)d_in[7];
    const float* bg      = (const float*)d_in[8];
    const float* wtb     = (const float*)d_in[9];
    const float* btb     = (const float*)d_in[10];
    const float* we1     = (const float*)d_in[11];
    const float* be1     = (const float*)d_in[12];
    const float* we2     = (const float*)d_in[13];
    const float* be2     = (const float*)d_in[14];
    const float* wm      = (const float*)d_in[15];
    const float* bm      = (const float*)d_in[16];
    const float* wo      = (const float*)d_in[17];
    const float* bo      = (const float*)d_in[18];
    const float* gamma   = (const float*)d_in[19];
    const float* beta    = (const float*)d_in[20];

    char* ws = (char*)d_ws;
    int* knn     = (int*)ws;                       // 64*256*16*4 = 1 MB
    float* gate  = (float*)(ws + (1 << 20));       // 64 KB
    float* tbias = gate + BB * H;                  // 64 KB
    float* MSG   = tbias + BB * H;                 // 16 MB

    knn_kernel<<<BB, NPT, 0, stream>>>(centers, knn);
    gate_kernel<<<BB, H, 0, stream>>>(textg, wg, bg, wtb, btb, gate, tbias);
    msg_kernel<<<BB * NPT / 8, H, 0, stream>>>(feat, wm, bm, MSG);
    edge_kernel<<<BB * NPT, H, 0, stream>>>(feat, centers, w1, b1, w2, b2,
                                            we1, be1, we2, be2, wo, bo, gamma, beta,
                                            knn, gate, tbias, MSG, (float*)d_out);
}

// Round 3
// 688.871 us; speedup vs baseline: 1.9100x; 1.9100x over previous
//
#include <hip/hip_runtime.h>

#define H 256
#define KNN 16
#define NPT 256
#define BB 64

typedef unsigned short u16;
typedef unsigned int u32;
typedef __attribute__((ext_vector_type(8))) short shortx8;
typedef __attribute__((ext_vector_type(4))) float floatx4;

__device__ __forceinline__ u16 f2b(float f) {
    u32 u = __float_as_uint(f);
    u32 r = (u + 0x7fffu + ((u >> 16) & 1u)) >> 16;  // RNE
    return (u16)r;
}

// ---------------------------------------------------------------------------
// K0: weight prep — bf16 transposed copies [n][k] for MFMA B-fragments.
// ---------------------------------------------------------------------------
__global__ __launch_bounds__(256) void prep_kernel(
    const float* __restrict__ w2, const float* __restrict__ we1,
    const float* __restrict__ wm, const float* __restrict__ wo,
    u16* __restrict__ w2t, u16* __restrict__ we1t,
    u16* __restrict__ wmt, u16* __restrict__ wot) {
    int tid = blockIdx.x * 256 + threadIdx.x;
    if (tid < 65536) {                       // w2t: 256 x 256
        int n = tid >> 8, k = tid & 255;
        w2t[tid] = f2b(w2[k * 256 + n]);
    } else if (tid < 98304) {                // we1t: 128 x 256
        int t = tid - 65536;
        int n = t >> 8, k = t & 255;
        we1t[t] = f2b(we1[k * 128 + n]);
    } else if (tid < 163840) {               // wmt: 256 x 256
        int t = tid - 98304;
        int n = t >> 8, k = t & 255;
        wmt[t] = f2b(wm[k * 256 + n]);
    } else if (tid < 294912) {               // wot: 256 x 512
        int t = tid - 163840;
        int n = t >> 9, k = t & 511;
        wot[t] = f2b(wo[k * 256 + n]);
    }
}

// ---------------------------------------------------------------------------
// K1: exact KNN (k=16), stable tie-break, matches jax.lax.top_k(-dist).
// ---------------------------------------------------------------------------
__global__ __launch_bounds__(NPT) void knn_kernel(const float* __restrict__ centers,
                                                  int* __restrict__ knn) {
    __shared__ float cx[NPT], cy[NPT], cz[NPT], sq[NPT];
    int b = blockIdx.x, n = threadIdx.x;
    const float* cb = centers + (size_t)b * NPT * 3;
    float x = cb[n * 3 + 0], y = cb[n * 3 + 1], z = cb[n * 3 + 2];
    cx[n] = x; cy[n] = y; cz[n] = z;
    sq[n] = x * x + y * y + z * z;
    __syncthreads();
    float bd[KNN];
    int bi[KNN];
#pragma unroll
    for (int j = 0; j < KNN; j++) { bd[j] = 1e30f; bi[j] = 0; }
    float sn = sq[n];
    for (int m = 0; m < NPT; m++) {
        float dot = x * cx[m] + y * cy[m] + z * cz[m];
        float d2 = (sn + sq[m]) - 2.0f * dot;
        float d = sqrtf(fmaxf(d2, 0.0f));
        if (d < bd[KNN - 1]) {
            bd[KNN - 1] = d; bi[KNN - 1] = m;
#pragma unroll
            for (int p = KNN - 1; p > 0; --p) {
                if (bd[p - 1] > bd[p]) {
                    float td = bd[p - 1]; bd[p - 1] = bd[p]; bd[p] = td;
                    int ti = bi[p - 1]; bi[p - 1] = bi[p]; bi[p] = ti;
                }
            }
        }
    }
    int* kp = knn + (b * NPT + n) * KNN;
#pragma unroll
    for (int j = 0; j < KNN; j++) kp[j] = bi[j];
}

// ---------------------------------------------------------------------------
// K2: text gate / bias per batch (f32 VALU — only 64 blocks, negligible).
// ---------------------------------------------------------------------------
__global__ __launch_bounds__(H) void gate_kernel(const float* __restrict__ tg_g,
                                                 const float* __restrict__ wg,
                                                 const float* __restrict__ bg,
                                                 const float* __restrict__ wtb,
                                                 const float* __restrict__ btb,
                                                 float* __restrict__ gate,
                                                 float* __restrict__ tbias) {
    __shared__ float tg[H];
    int b = blockIdx.x, h = threadIdx.x;
    tg[h] = tg_g[b * H + h];
    __syncthreads();
    float ag = bg[h], ab = btb[h];
    for (int i = 0; i < H; i++) {
        float t = tg[i];
        ag += t * wg[i * H + h];
        ab += t * wtb[i * H + h];
    }
    gate[b * H + h] = 1.0f / (1.0f + expf(-ag));
    tbias[b * H + h] = ab;
}

// ---------------------------------------------------------------------------
// K3: MSG = relu(feat @ Wm + bm), MFMA, 16 points per block.
// ---------------------------------------------------------------------------
__global__ __launch_bounds__(256) void msg_mfma(const float* __restrict__ feat,
                                                const u16* __restrict__ wmt,
                                                const float* __restrict__ bm,
                                                float* __restrict__ MSG) {
    __shared__ __attribute__((aligned(16))) u16 A[16][264];
    int p0 = blockIdx.x * 16, t = threadIdx.x;
#pragma unroll
    for (int j = 0; j < 16; j++) A[j][t] = f2b(feat[(size_t)(p0 + j) * H + t]);
    __syncthreads();
    int w = t >> 6, lane = t & 63, quad = lane >> 4, lq = lane & 15;
    floatx4 acc[4] = {{0,0,0,0},{0,0,0,0},{0,0,0,0},{0,0,0,0}};
    for (int kt = 0; kt < 8; kt++) {
        shortx8 a = *(const shortx8*)&A[lq][kt * 32 + quad * 8];
#pragma unroll
        for (int tt = 0; tt < 4; tt++) {
            int nn = w * 64 + tt * 16 + lq;
            shortx8 bf = *(const shortx8*)&wmt[nn * 256 + kt * 32 + quad * 8];
            acc[tt] = __builtin_amdgcn_mfma_f32_16x16x32_bf16(a, bf, acc[tt], 0, 0, 0);
        }
    }
#pragma unroll
    for (int tt = 0; tt < 4; tt++) {
        int col = w * 64 + tt * 16 + lq;
        float bmc = bm[col];
#pragma unroll
        for (int r = 0; r < 4; r++) {
            int row = quad * 4 + r;
            MSG[(size_t)(p0 + row) * H + col] = fmaxf(acc[tt][r] + bmc, 0.0f);
        }
    }
}

// ---------------------------------------------------------------------------
// K4: fused edge pipeline, MFMA for the two big GEMMs. One block per point.
// Writes ctx to ws; out-proj+LN moved to K5.
// ---------------------------------------------------------------------------
__global__ __launch_bounds__(256) void edge_mfma(
    const float* __restrict__ feat, const float* __restrict__ centers,
    const float* __restrict__ w1, const float* __restrict__ b1,
    const u16* __restrict__ w2t, const float* __restrict__ b2v,
    const u16* __restrict__ we1t, const float* __restrict__ be1,
    const float* __restrict__ we2, const float* __restrict__ be2,
    const int* __restrict__ knn, const float* __restrict__ gate,
    const float* __restrict__ tbias, const float* __restrict__ MSG,
    float* __restrict__ ctxG) {
    __shared__ float fn[H];
    __shared__ float fnbS[KNN][H + 1];
    __shared__ __attribute__((aligned(16))) u16 A[KNN][264];  // g1 then edge_feat, bf16 [m][k]
    __shared__ float geomS[KNN][4];
    __shared__ int nidxS[KNN];
    __shared__ float part[4][KNN];
    __shared__ float logitsS[KNN];
    __shared__ float alphaS[KNN];

    int bn = blockIdx.x, b = bn >> 8, n = bn & 255, h = threadIdx.x;
    int w = h >> 6, lane = h & 63, quad = lane >> 4, lq = lane & 15;

    fn[h] = feat[(size_t)bn * H + h];
    if (h < KNN) nidxS[h] = knn[bn * KNN + h];
    __syncthreads();
#pragma unroll
    for (int j = 0; j < KNN; j++)
        fnbS[j][h] = feat[((size_t)b * NPT + nidxS[j]) * H + h];
    if (h < KNN) {
        int m = nidxS[h];
        const float* cb = centers + (size_t)b * NPT * 3;
        float rx = cb[m * 3 + 0] - cb[n * 3 + 0];
        float ry = cb[m * 3 + 1] - cb[n * 3 + 1];
        float rz = cb[m * 3 + 2] - cb[n * 3 + 2];
        float dist = sqrtf(rx * rx + ry * ry + rz * rz) + 1e-6f;
        geomS[h][0] = rx; geomS[h][1] = ry; geomS[h][2] = rz;
        geomS[h][3] = log1pf(dist);
    }
    __syncthreads();

    // g1[j][h] = relu(geom[j] @ W1[:,h] + b1[h]) -> bf16 A[j][h]
    {
        float c0 = w1[h], c1 = w1[H + h], c2 = w1[2 * H + h], c3 = w1[3 * H + h];
        float bb = b1[h];
#pragma unroll
        for (int j = 0; j < KNN; j++) {
            float g = fmaxf(bb + geomS[j][0] * c0 + geomS[j][1] * c1 +
                            geomS[j][2] * c2 + geomS[j][3] * c3, 0.0f);
            A[j][h] = f2b(g);
        }
    }
    __syncthreads();

    // GEMM1: C1[16 edges][256] = g1 @ W2  (MFMA 16x16x32 bf16)
    floatx4 acc1[4] = {{0,0,0,0},{0,0,0,0},{0,0,0,0},{0,0,0,0}};
    for (int kt = 0; kt < 8; kt++) {
        shortx8 a = *(const shortx8*)&A[lq][kt * 32 + quad * 8];
#pragma unroll
        for (int tt = 0; tt < 4; tt++) {
            int nn = w * 64 + tt * 16 + lq;
            shortx8 bf = *(const shortx8*)&w2t[nn * 256 + kt * 32 + quad * 8];
            acc1[tt] = __builtin_amdgcn_mfma_f32_16x16x32_bf16(a, bf, acc1[tt], 0, 0, 0);
        }
    }

    // epilogue1: edge_feat = tanh(fn + fnb + relu(C1+b2)*gate + tbias)
    float ef[16];
#pragma unroll
    for (int tt = 0; tt < 4; tt++) {
        int col = w * 64 + tt * 16 + lq;
        float b2c = b2v[col];
        float gc = gate[b * H + col];
        float tc = tbias[b * H + col];
        float fnc = fn[col];
#pragma unroll
        for (int r = 0; r < 4; r++) {
            int row = quad * 4 + r;
            float emb = fmaxf(acc1[tt][r] + b2c, 0.0f);
            float cond = emb * gc + tc;
            ef[tt * 4 + r] = tanhf(fnc + fnbS[row][col] + cond);
        }
    }
    __syncthreads();  // all waves done reading A (g1)
#pragma unroll
    for (int tt = 0; tt < 4; tt++) {
        int col = w * 64 + tt * 16 + lq;
#pragma unroll
        for (int r = 0; r < 4; r++) A[quad * 4 + r][col] = f2b(ef[tt * 4 + r]);
    }
    __syncthreads();

    // GEMM2: C2[16 edges][128] = edge_feat @ We1
    floatx4 acc2[2] = {{0,0,0,0},{0,0,0,0}};
    for (int kt = 0; kt < 8; kt++) {
        shortx8 a = *(const shortx8*)&A[lq][kt * 32 + quad * 8];
#pragma unroll
        for (int tt = 0; tt < 2; tt++) {
            int nn = w * 32 + tt * 16 + lq;
            shortx8 bf = *(const shortx8*)&we1t[nn * 256 + kt * 32 + quad * 8];
            acc2[tt] = __builtin_amdgcn_mfma_f32_16x16x32_bf16(a, bf, acc2[tt], 0, 0, 0);
        }
    }

    // logits: p[row] = sum_col relu(C2+be1)*we2
    float p[4] = {0, 0, 0, 0};
#pragma unroll
    for (int tt = 0; tt < 2; tt++) {
        int col = w * 32 + tt * 16 + lq;
        float be1c = be1[col], w2c = we2[col];
#pragma unroll
        for (int r = 0; r < 4; r++)
            p[r] += fmaxf(acc2[tt][r] + be1c, 0.0f) * w2c;
    }
#pragma unroll
    for (int d = 1; d < 16; d <<= 1) {
#pragma unroll
        for (int r = 0; r < 4; r++) p[r] += __shfl_xor(p[r], d, 16);
    }
    if (lq == 0) {
#pragma unroll
        for (int r = 0; r < 4; r++) part[w][quad * 4 + r] = p[r];
    }
    __syncthreads();
    if (h < KNN)
        logitsS[h] = part[0][h] + part[1][h] + part[2][h] + part[3][h] + be2[0];
    __syncthreads();
    if (h < KNN) {
        float mx = -1e30f;
#pragma unroll
        for (int j = 0; j < KNN; j++) mx = fmaxf(mx, logitsS[j]);
        float s = 0.0f;
#pragma unroll
        for (int j = 0; j < KNN; j++) s += expf(logitsS[j] - mx);
        alphaS[h] = expf(logitsS[h] - mx) / s;
    }
    __syncthreads();

    // ctx[h] = sum_j alpha[j] * MSG[nidx[j]][h]
    float c = 0.0f;
#pragma unroll
    for (int j = 0; j < KNN; j++)
        c += alphaS[j] * MSG[((size_t)b * NPT + nidxS[j]) * H + h];
    ctxG[(size_t)bn * H + h] = c;
}

// ---------------------------------------------------------------------------
// K5: out = LN(feat + relu([feat|ctx] @ Wo + bo)), MFMA, 16 points/block.
// ---------------------------------------------------------------------------
__global__ __launch_bounds__(256) void out_mfma(const float* __restrict__ feat,
                                                const float* __restrict__ ctxG,
                                                const u16* __restrict__ wot,
                                                const float* __restrict__ bo,
                                                const float* __restrict__ gamma,
                                                const float* __restrict__ beta,
                                                float* __restrict__ out) {
    __shared__ __attribute__((aligned(16))) u16 A[16][520];
    __shared__ float redS[4][16], redS2[4][16];
    int p0 = blockIdx.x * 16, t = threadIdx.x;
    int w = t >> 6, lane = t & 63, quad = lane >> 4, lq = lane & 15;
#pragma unroll
    for (int j = 0; j < 16; j++) {
        A[j][t]       = f2b(feat[(size_t)(p0 + j) * H + t]);
        A[j][256 + t] = f2b(ctxG[(size_t)(p0 + j) * H + t]);
    }
    __syncthreads();
    floatx4 acc[4] = {{0,0,0,0},{0,0,0,0},{0,0,0,0},{0,0,0,0}};
    for (int kt = 0; kt < 16; kt++) {
        shortx8 a = *(const shortx8*)&A[lq][kt * 32 + quad * 8];
#pragma unroll
        for (int tt = 0; tt < 4; tt++) {
            int nn = w * 64 + tt * 16 + lq;
            shortx8 bf = *(const shortx8*)&wot[nn * 512 + kt * 32 + quad * 8];
            acc[tt] = __builtin_amdgcn_mfma_f32_16x16x32_bf16(a, bf, acc[tt], 0, 0, 0);
        }
    }
    float x[16];
    float sm[4] = {0, 0, 0, 0}, sq[4] = {0, 0, 0, 0};
#pragma unroll
    for (int tt = 0; tt < 4; tt++) {
        int col = w * 64 + tt * 16 + lq;
        float boc = bo[col];
#pragma unroll
        for (int r = 0; r < 4; r++) {
            int row = quad * 4 + r;
            float xx = feat[(size_t)(p0 + row) * H + col] + fmaxf(acc[tt][r] + boc, 0.0f);
            x[tt * 4 + r] = xx;
            sm[r] += xx;
            sq[r] += xx * xx;
        }
    }
#pragma unroll
    for (int d = 1; d < 16; d <<= 1) {
#pragma unroll
        for (int r = 0; r < 4; r++) {
            sm[r] += __shfl_xor(sm[r], d, 16);
            sq[r] += __shfl_xor(sq[r], d, 16);
        }
    }
    if (lq == 0) {
#pragma unroll
        for (int r = 0; r < 4; r++) {
            redS[w][quad * 4 + r] = sm[r];
            redS2[w][quad * 4 + r] = sq[r];
        }
    }
    __syncthreads();
#pragma unroll
    for (int r = 0; r < 4; r++) {
        int row = quad * 4 + r;
        float s1 = redS[0][row] + redS[1][row] + redS[2][row] + redS[3][row];
        float s2 = redS2[0][row] + redS2[1][row] + redS2[2][row] + redS2[3][row];
        float mu = s1 * (1.0f / H);
        float var = s2 * (1.0f / H) - mu * mu;
        float inv = rsqrtf(fmaxf(var, 0.0f) + 1e-5f);
#pragma unroll
        for (int tt = 0; tt < 4; tt++) {
            int col = w * 64 + tt * 16 + lq;
            out[(size_t)(p0 + row) * H + col] =
                (x[tt * 4 + r] - mu) * inv * gamma[col] + beta[col];
        }
    }
}

// ---------------------------------------------------------------------------
extern "C" void kernel_launch(void* const* d_in, const int* in_sizes, int n_in,
                              void* d_out, int out_size, void* d_ws, size_t ws_size,
                              hipStream_t stream) {
    const float* feat    = (const float*)d_in[0];
    const float* centers = (const float*)d_in[1];
    const float* textg   = (const float*)d_in[2];
    const float* w1      = (const float*)d_in[3];
    const float* b1      = (const float*)d_in[4];
    const float* w2      = (const float*)d_in[5];
    const float* b2      = (const float*)d_in[6];
    const float* wg      = (const float*)d_in[7];
    const float* bg      = (const float*)d_in[8];
    const float* wtb     = (const float*)d_in[9];
    const float* btb     = (const float*)d_in[10];
    const float* we1     = (const float*)d_in[11];
    const float* be1     = (const float*)d_in[12];
    const float* we2     = (const float*)d_in[13];
    const float* be2     = (const float*)d_in[14];
    const float* wm      = (const float*)d_in[15];
    const float* bm      = (const float*)d_in[16];
    const float* wo      = (const float*)d_in[17];
    const float* bo      = (const float*)d_in[18];
    const float* gamma   = (const float*)d_in[19];
    const float* beta    = (const float*)d_in[20];

    char* ws = (char*)d_ws;
    size_t off = 0;
    int* knn     = (int*)(ws + off);   off += (size_t)BB * NPT * KNN * 4;   // 1 MB
    float* gate  = (float*)(ws + off); off += (size_t)BB * H * 4;           // 64 KB
    float* tbias = (float*)(ws + off); off += (size_t)BB * H * 4;           // 64 KB
    float* MSG   = (float*)(ws + off); off += (size_t)BB * NPT * H * 4;     // 16 MB
    float* ctxG  = (float*)(ws + off); off += (size_t)BB * NPT * H * 4;     // 16 MB
    u16* w2t     = (u16*)(ws + off);   off += (size_t)256 * 256 * 2;        // 128 KB
    u16* we1t    = (u16*)(ws + off);   off += (size_t)128 * 256 * 2;        // 64 KB
    u16* wmt     = (u16*)(ws + off);   off += (size_t)256 * 256 * 2;        // 128 KB
    u16* wot     = (u16*)(ws + off);   off += (size_t)256 * 512 * 2;        // 256 KB

    prep_kernel<<<1152, 256, 0, stream>>>(w2, we1, wm, wo, w2t, we1t, wmt, wot);
    knn_kernel<<<BB, NPT, 0, stream>>>(centers, knn);
    gate_kernel<<<BB, H, 0, stream>>>(textg, wg, bg, wtb, btb, gate, tbias);
    msg_mfma<<<BB * NPT / 16, 256, 0, stream>>>(feat, wmt, bm, MSG);
    edge_mfma<<<BB * NPT, 256, 0, stream>>>(feat, centers, w1, b1, w2t, b2,
                                            we1t, be1, we2, be2, knn, gate, tbias,
                                            MSG, ctxG);
    out_mfma<<<BB * NPT / 16, 256, 0, stream>>>(feat, ctxG, wot, bo, gamma, beta,
                                                (float*)d_out);
}

// Round 4
// 365.928 us; speedup vs baseline: 3.5956x; 1.8825x over previous
//
#include <hip/hip_runtime.h>

#define H 256
#define KNN 16
#define NPT 256
#define BB 64

typedef unsigned short u16;
typedef unsigned int u32;
typedef __attribute__((ext_vector_type(8))) short shortx8;
typedef __attribute__((ext_vector_type(4))) float floatx4;

__device__ __forceinline__ u16 f2b(float f) {
    u32 u = __float_as_uint(f);
    u32 r = (u + 0x7fffu + ((u >> 16) & 1u)) >> 16;  // RNE
    return (u16)r;
}

// tanh via hw exp2: 1 - 2/(exp2(x*2log2e)+1). |err| ~1e-6, saturates correctly.
__device__ __forceinline__ float fast_tanh(float x) {
    float e = __builtin_amdgcn_exp2f(x * 2.88539008177793f);
    return 1.0f - 2.0f * __builtin_amdgcn_rcpf(e + 1.0f);
}

// ---------------------------------------------------------------------------
// K0: weight prep — bf16 transposed copies [n][k] for MFMA B-fragments.
// ---------------------------------------------------------------------------
__global__ __launch_bounds__(256) void prep_kernel(
    const float* __restrict__ w2, const float* __restrict__ we1,
    const float* __restrict__ wm, const float* __restrict__ wo,
    u16* __restrict__ w2t, u16* __restrict__ we1t,
    u16* __restrict__ wmt, u16* __restrict__ wot) {
    int tid = blockIdx.x * 256 + threadIdx.x;
    if (tid < 65536) {                       // w2t: 256 x 256
        int n = tid >> 8, k = tid & 255;
        w2t[tid] = f2b(w2[k * 256 + n]);
    } else if (tid < 98304) {                // we1t: 128 x 256
        int t = tid - 65536;
        int n = t >> 8, k = t & 255;
        we1t[t] = f2b(we1[k * 128 + n]);
    } else if (tid < 163840) {               // wmt: 256 x 256
        int t = tid - 98304;
        int n = t >> 8, k = t & 255;
        wmt[t] = f2b(wm[k * 256 + n]);
    } else if (tid < 294912) {               // wot: 256 x 512
        int t = tid - 163840;
        int n = t >> 9, k = t & 511;
        wot[t] = f2b(wo[k * 256 + n]);
    }
}

// ---------------------------------------------------------------------------
// K1: exact KNN k=16, stable (d, idx)-lexicographic == jax.lax.top_k(-dist).
// 256 blocks: block = (batch, quarter of points). 4 scanner-waves per point
// group; wave s scans m in [s*64, s*64+64); wave 0 merges.
// ---------------------------------------------------------------------------
__global__ __launch_bounds__(256) void knn_kernel(const float* __restrict__ centers,
                                                  int* __restrict__ knn) {
    __shared__ float cx[NPT], cy[NPT], cz[NPT], sq[NPT];
    __shared__ float dl[4][64][17];
    __shared__ int il[4][64][17];
    int blk = blockIdx.x;
    int b = blk >> 2, n0 = (blk & 3) * 64;
    int h = threadIdx.x;
    int s = h >> 6, pt = h & 63;
    {
        const float* cb = centers + (size_t)b * NPT * 3;
        float x = cb[h * 3 + 0], y = cb[h * 3 + 1], z = cb[h * 3 + 2];
        cx[h] = x; cy[h] = y; cz[h] = z;
        sq[h] = x * x + y * y + z * z;
    }
    __syncthreads();
    int n = n0 + pt;
    float x = cx[n], y = cy[n], z = cz[n], sn = sq[n];
    float bd[KNN];
    int bi[KNN];
#pragma unroll
    for (int j = 0; j < KNN; j++) { bd[j] = 1e30f; bi[j] = 0x7fffffff; }
    for (int mm = 0; mm < 64; mm++) {
        int m = s * 64 + mm;
        float dot = x * cx[m] + y * cy[m] + z * cz[m];
        float d2 = (sn + sq[m]) - 2.0f * dot;
        float d = sqrtf(fmaxf(d2, 0.0f));
        if (d < bd[KNN - 1]) {  // in-order scan + strict < == lexicographic
            bd[KNN - 1] = d; bi[KNN - 1] = m;
#pragma unroll
            for (int p = KNN - 1; p > 0; --p) {
                if (bd[p - 1] > bd[p]) {
                    float td = bd[p - 1]; bd[p - 1] = bd[p]; bd[p] = td;
                    int ti = bi[p - 1]; bi[p - 1] = bi[p]; bi[p] = ti;
                }
            }
        }
    }
#pragma unroll
    for (int j = 0; j < KNN; j++) { dl[s][pt][j] = bd[j]; il[s][pt][j] = bi[j]; }
    __syncthreads();
    if (s == 0) {
        float md[KNN];
        int mi[KNN];
#pragma unroll
        for (int j = 0; j < KNN; j++) { md[j] = dl[0][pt][j]; mi[j] = il[0][pt][j]; }
        for (int t = 1; t < 4; t++) {
            for (int j = 0; j < KNN; j++) {
                float d = dl[t][pt][j];
                int idx = il[t][pt][j];
                bool ins = (d < md[KNN - 1]) || (d == md[KNN - 1] && idx < mi[KNN - 1]);
                if (!ins) break;  // source list sorted lexicographically
                md[KNN - 1] = d; mi[KNN - 1] = idx;
#pragma unroll
                for (int p = KNN - 1; p > 0; --p) {
                    bool sw = (md[p - 1] > md[p]) ||
                              (md[p - 1] == md[p] && mi[p - 1] > mi[p]);
                    if (sw) {
                        float td = md[p - 1]; md[p - 1] = md[p]; md[p] = td;
                        int ti = mi[p - 1]; mi[p - 1] = mi[p]; mi[p] = ti;
                    }
                }
            }
        }
        int* kp = knn + (b * NPT + n0 + pt) * KNN;
#pragma unroll
        for (int j = 0; j < KNN; j++) kp[j] = mi[j];
    }
}

// ---------------------------------------------------------------------------
// K2: text gate / bias per batch. 512 threads: 0..255 gate, 256..511 tbias.
// ---------------------------------------------------------------------------
__global__ __launch_bounds__(512) void gate_kernel(const float* __restrict__ tg_g,
                                                   const float* __restrict__ wg,
                                                   const float* __restrict__ bg,
                                                   const float* __restrict__ wtb,
                                                   const float* __restrict__ btb,
                                                   float* __restrict__ gate,
                                                   float* __restrict__ tbias) {
    __shared__ float tg[H];
    int b = blockIdx.x, t = threadIdx.x;
    if (t < H) tg[t] = tg_g[b * H + t];
    __syncthreads();
    int h = t & 255;
    if (t < H) {
        float ag = bg[h];
#pragma unroll 4
        for (int i = 0; i < H; i++) ag += tg[i] * wg[i * H + h];
        gate[b * H + h] = 1.0f / (1.0f + expf(-ag));
    } else {
        float ab = btb[h];
#pragma unroll 4
        for (int i = 0; i < H; i++) ab += tg[i] * wtb[i * H + h];
        tbias[b * H + h] = ab;
    }
}

// ---------------------------------------------------------------------------
// K3: MSG = relu(feat @ Wm + bm), MFMA, 64 points/block (M=64, B reuse x4).
// ---------------------------------------------------------------------------
__global__ __launch_bounds__(256, 4) void msg_mfma(const float* __restrict__ feat,
                                                   const u16* __restrict__ wmt,
                                                   const float* __restrict__ bm,
                                                   float* __restrict__ MSG) {
    __shared__ __attribute__((aligned(16))) u16 A[64][264];
    int p0 = blockIdx.x * 64, h = threadIdx.x;
    int w = h >> 6, lane = h & 63, quad = lane >> 4, lq = lane & 15;
#pragma unroll 8
    for (int row = 0; row < 64; row++)
        A[row][h] = f2b(feat[(size_t)(p0 + row) * H + h]);
    __syncthreads();
    floatx4 acc[4][4];
#pragma unroll
    for (int rt = 0; rt < 4; rt++)
#pragma unroll
        for (int ct = 0; ct < 4; ct++) acc[rt][ct] = (floatx4){0, 0, 0, 0};
#pragma unroll 2
    for (int kt = 0; kt < 8; kt++) {
        shortx8 bf[4];
#pragma unroll
        for (int ct = 0; ct < 4; ct++)
            bf[ct] = *(const shortx8*)&wmt[(w * 64 + ct * 16 + lq) * 256 + kt * 32 + quad * 8];
#pragma unroll
        for (int rt = 0; rt < 4; rt++) {
            shortx8 a = *(const shortx8*)&A[rt * 16 + lq][kt * 32 + quad * 8];
#pragma unroll
            for (int ct = 0; ct < 4; ct++)
                acc[rt][ct] = __builtin_amdgcn_mfma_f32_16x16x32_bf16(a, bf[ct], acc[rt][ct], 0, 0, 0);
        }
    }
#pragma unroll
    for (int ct = 0; ct < 4; ct++) {
        int col = w * 64 + ct * 16 + lq;
        float bmc = bm[col];
#pragma unroll
        for (int rt = 0; rt < 4; rt++)
#pragma unroll
            for (int r = 0; r < 4; r++) {
                int row = rt * 16 + quad * 4 + r;
                MSG[(size_t)(p0 + row) * H + col] = fmaxf(acc[rt][ct][r] + bmc, 0.0f);
            }
    }
}

// ---------------------------------------------------------------------------
// K4: fused edge pipeline, 4 points/block (M=64 edges). MFMA GEMMs with
// B-fragment register reuse x4. ~40.7 KB LDS -> 4 blocks/CU.
// ---------------------------------------------------------------------------
__global__ __launch_bounds__(256, 4) void edge_mfma(
    const float* __restrict__ feat, const float* __restrict__ centers,
    const float* __restrict__ w1, const float* __restrict__ b1,
    const u16* __restrict__ w2t, const float* __restrict__ b2v,
    const u16* __restrict__ we1t, const float* __restrict__ be1,
    const float* __restrict__ we2, const float* __restrict__ be2,
    const int* __restrict__ knn, const float* __restrict__ gateG,
    const float* __restrict__ tbiasG, const float* __restrict__ MSG,
    float* __restrict__ ctxG) {
    __shared__ __attribute__((aligned(16))) u16 A[64][264];  // g1 then edge_feat
    __shared__ float fnS[4][H];
    __shared__ __attribute__((aligned(16))) float geomS[64][4];
    __shared__ int nidxS[64];
    __shared__ float part[4][64];
    __shared__ float logitsS[64];
    __shared__ float alphaS[64];

    int bn0 = blockIdx.x * 4;
    int b = bn0 >> 8, n0 = bn0 & 255;
    int h = threadIdx.x;
    int w = h >> 6, lane = h & 63, quad = lane >> 4, lq = lane & 15;

    // phase 0: nidx + fn staging
    if (h < 64) nidxS[h] = knn[bn0 * KNN + h];
#pragma unroll
    for (int p = 0; p < 4; p++)
        fnS[p][h] = feat[(size_t)(bn0 + p) * H + h];
    __syncthreads();

    // phase 1: geom per edge-row (h<64: point p=h>>4, neighbor j=h&15)
    if (h < 64) {
        int p = h >> 4;
        int m = nidxS[h];
        int n = n0 + p;
        const float* cb = centers + (size_t)b * NPT * 3;
        float rx = cb[m * 3 + 0] - cb[n * 3 + 0];
        float ry = cb[m * 3 + 1] - cb[n * 3 + 1];
        float rz = cb[m * 3 + 2] - cb[n * 3 + 2];
        float dist = sqrtf(rx * rx + ry * ry + rz * rz) + 1e-6f;
        geomS[h][0] = rx; geomS[h][1] = ry; geomS[h][2] = rz;
        geomS[h][3] = log1pf(dist);
    }
    __syncthreads();

    // phase 2: g1[row][h] = relu(geom[row] @ W1[:,h] + b1[h]) -> bf16 A
    {
        float c0 = w1[h], c1 = w1[H + h], c2 = w1[2 * H + h], c3 = w1[3 * H + h];
        float bb = b1[h];
#pragma unroll 8
        for (int row = 0; row < 64; row++) {
            float4 g = *(const float4*)&geomS[row][0];
            float v = fmaxf(bb + g.x * c0 + g.y * c1 + g.z * c2 + g.w * c3, 0.0f);
            A[row][h] = f2b(v);
        }
    }
    __syncthreads();

    // GEMM1: C1[64][256] = g1 @ W2
    floatx4 acc[4][4];
#pragma unroll
    for (int rt = 0; rt < 4; rt++)
#pragma unroll
        for (int ct = 0; ct < 4; ct++) acc[rt][ct] = (floatx4){0, 0, 0, 0};
#pragma unroll 2
    for (int kt = 0; kt < 8; kt++) {
        shortx8 bf[4];
#pragma unroll
        for (int ct = 0; ct < 4; ct++)
            bf[ct] = *(const shortx8*)&w2t[(w * 64 + ct * 16 + lq) * 256 + kt * 32 + quad * 8];
#pragma unroll
        for (int rt = 0; rt < 4; rt++) {
            shortx8 a = *(const shortx8*)&A[rt * 16 + lq][kt * 32 + quad * 8];
#pragma unroll
            for (int ct = 0; ct < 4; ct++)
                acc[rt][ct] = __builtin_amdgcn_mfma_f32_16x16x32_bf16(a, bf[ct], acc[rt][ct], 0, 0, 0);
        }
    }
    __syncthreads();  // all g1 reads done

    // epilogue1: edge_feat = tanh(fn + fnb + relu(C1+b2)*gate + tbias) -> A
#pragma unroll
    for (int ct = 0; ct < 4; ct++) {
        int col = w * 64 + ct * 16 + lq;
        float b2c = b2v[col];
        float gc = gateG[b * H + col];
        float tc = tbiasG[b * H + col];
#pragma unroll
        for (int rt = 0; rt < 4; rt++) {
            float fnc = fnS[rt][col];
#pragma unroll
            for (int r = 0; r < 4; r++) {
                int row = rt * 16 + quad * 4 + r;
                float fb = feat[((size_t)b * NPT + nidxS[row]) * H + col];
                float emb = fmaxf(acc[rt][ct][r] + b2c, 0.0f);
                float ef = fast_tanh(fnc + fb + emb * gc + tc);
                A[row][col] = f2b(ef);
            }
        }
    }
    __syncthreads();

    // GEMM2: C2[64][128] = edge_feat @ We1
    floatx4 acc2[4][2];
#pragma unroll
    for (int rt = 0; rt < 4; rt++)
#pragma unroll
        for (int c2 = 0; c2 < 2; c2++) acc2[rt][c2] = (floatx4){0, 0, 0, 0};
#pragma unroll 2
    for (int kt = 0; kt < 8; kt++) {
        shortx8 bf[2];
#pragma unroll
        for (int c2 = 0; c2 < 2; c2++)
            bf[c2] = *(const shortx8*)&we1t[(w * 32 + c2 * 16 + lq) * 256 + kt * 32 + quad * 8];
#pragma unroll
        for (int rt = 0; rt < 4; rt++) {
            shortx8 a = *(const shortx8*)&A[rt * 16 + lq][kt * 32 + quad * 8];
#pragma unroll
            for (int c2 = 0; c2 < 2; c2++)
                acc2[rt][c2] = __builtin_amdgcn_mfma_f32_16x16x32_bf16(a, bf[c2], acc2[rt][c2], 0, 0, 0);
        }
    }

    // logits partials
    float pl[4][4];
#pragma unroll
    for (int rt = 0; rt < 4; rt++)
#pragma unroll
        for (int r = 0; r < 4; r++) pl[rt][r] = 0.0f;
#pragma unroll
    for (int c2 = 0; c2 < 2; c2++) {
        int col = w * 32 + c2 * 16 + lq;
        float be1c = be1[col], w2c = we2[col];
#pragma unroll
        for (int rt = 0; rt < 4; rt++)
#pragma unroll
            for (int r = 0; r < 4; r++)
                pl[rt][r] += fmaxf(acc2[rt][c2][r] + be1c, 0.0f) * w2c;
    }
#pragma unroll
    for (int d = 1; d < 16; d <<= 1)
#pragma unroll
        for (int rt = 0; rt < 4; rt++)
#pragma unroll
            for (int r = 0; r < 4; r++) pl[rt][r] += __shfl_xor(pl[rt][r], d, 16);
    if (lq == 0) {
#pragma unroll
        for (int rt = 0; rt < 4; rt++)
#pragma unroll
            for (int r = 0; r < 4; r++)
                part[w][rt * 16 + quad * 4 + r] = pl[rt][r];
    }
    __syncthreads();
    if (h < 64)
        logitsS[h] = part[0][h] + part[1][h] + part[2][h] + part[3][h] + be2[0];
    __syncthreads();
    if (h < 64) {
        int base = (h >> 4) * 16;
        float mx = -1e30f;
#pragma unroll
        for (int j = 0; j < KNN; j++) mx = fmaxf(mx, logitsS[base + j]);
        float sum = 0.0f;
#pragma unroll
        for (int j = 0; j < KNN; j++) sum += expf(logitsS[base + j] - mx);
        alphaS[h] = expf(logitsS[h] - mx) / sum;
    }
    __syncthreads();

    // ctx[p][h] = sum_j alpha * MSG[nidx][h]
    float c[4] = {0, 0, 0, 0};
#pragma unroll 16
    for (int row = 0; row < 64; row++) {
        float al = alphaS[row];
        c[row >> 4] += al * MSG[((size_t)b * NPT + nidxS[row]) * H + h];
    }
#pragma unroll
    for (int p = 0; p < 4; p++)
        ctxG[(size_t)(bn0 + p) * H + h] = c[p];
}

// ---------------------------------------------------------------------------
// K5: out = LN(feat + relu([feat|ctx] @ Wo + bo)), MFMA, 32 points/block.
// ---------------------------------------------------------------------------
__global__ __launch_bounds__(256, 4) void out_mfma(const float* __restrict__ feat,
                                                   const float* __restrict__ ctxG,
                                                   const u16* __restrict__ wot,
                                                   const float* __restrict__ bo,
                                                   const float* __restrict__ gamma,
                                                   const float* __restrict__ beta,
                                                   float* __restrict__ out) {
    __shared__ __attribute__((aligned(16))) u16 A[32][520];
    __shared__ float redS[4][32], redS2[4][32];
    int p0 = blockIdx.x * 32, h = threadIdx.x;
    int w = h >> 6, lane = h & 63, quad = lane >> 4, lq = lane & 15;
#pragma unroll 8
    for (int row = 0; row < 32; row++) {
        A[row][h]       = f2b(feat[(size_t)(p0 + row) * H + h]);
        A[row][256 + h] = f2b(ctxG[(size_t)(p0 + row) * H + h]);
    }
    __syncthreads();
    floatx4 acc[2][4];
#pragma unroll
    for (int rt = 0; rt < 2; rt++)
#pragma unroll
        for (int ct = 0; ct < 4; ct++) acc[rt][ct] = (floatx4){0, 0, 0, 0};
#pragma unroll 2
    for (int kt = 0; kt < 16; kt++) {
        shortx8 bf[4];
#pragma unroll
        for (int ct = 0; ct < 4; ct++)
            bf[ct] = *(const shortx8*)&wot[(w * 64 + ct * 16 + lq) * 512 + kt * 32 + quad * 8];
#pragma unroll
        for (int rt = 0; rt < 2; rt++) {
            shortx8 a = *(const shortx8*)&A[rt * 16 + lq][kt * 32 + quad * 8];
#pragma unroll
            for (int ct = 0; ct < 4; ct++)
                acc[rt][ct] = __builtin_amdgcn_mfma_f32_16x16x32_bf16(a, bf[ct], acc[rt][ct], 0, 0, 0);
        }
    }
    float x[2][4][4];
    float sm[2][4], sq2[2][4];
#pragma unroll
    for (int rt = 0; rt < 2; rt++)
#pragma unroll
        for (int r = 0; r < 4; r++) { sm[rt][r] = 0.0f; sq2[rt][r] = 0.0f; }
#pragma unroll
    for (int rt = 0; rt < 2; rt++)
#pragma unroll
        for (int ct = 0; ct < 4; ct++) {
            int col = w * 64 + ct * 16 + lq;
            float boc = bo[col];
#pragma unroll
            for (int r = 0; r < 4; r++) {
                int row = rt * 16 + quad * 4 + r;
                float xx = feat[(size_t)(p0 + row) * H + col] +
                           fmaxf(acc[rt][ct][r] + boc, 0.0f);
                x[rt][ct][r] = xx;
                sm[rt][r] += xx;
                sq2[rt][r] += xx * xx;
            }
        }
#pragma unroll
    for (int d = 1; d < 16; d <<= 1)
#pragma unroll
        for (int rt = 0; rt < 2; rt++)
#pragma unroll
            for (int r = 0; r < 4; r++) {
                sm[rt][r] += __shfl_xor(sm[rt][r], d, 16);
                sq2[rt][r] += __shfl_xor(sq2[rt][r], d, 16);
            }
    if (lq == 0) {
#pragma unroll
        for (int rt = 0; rt < 2; rt++)
#pragma unroll
            for (int r = 0; r < 4; r++) {
                redS[w][rt * 16 + quad * 4 + r] = sm[rt][r];
                redS2[w][rt * 16 + quad * 4 + r] = sq2[rt][r];
            }
    }
    __syncthreads();
#pragma unroll
    for (int rt = 0; rt < 2; rt++)
#pragma unroll
        for (int r = 0; r < 4; r++) {
            int row = rt * 16 + quad * 4 + r;
            float s1 = redS[0][row] + redS[1][row] + redS[2][row] + redS[3][row];
            float s2 = redS2[0][row] + redS2[1][row] + redS2[2][row] + redS2[3][row];
            float mu = s1 * (1.0f / H);
            float var = s2 * (1.0f / H) - mu * mu;
            float inv = rsqrtf(fmaxf(var, 0.0f) + 1e-5f);
#pragma unroll
            for (int ct = 0; ct < 4; ct++) {
                int col = w * 64 + ct * 16 + lq;
                out[(size_t)(p0 + row) * H + col] =
                    (x[rt][ct][r] - mu) * inv * gamma[col] + beta[col];
            }
        }
}

// ---------------------------------------------------------------------------
extern "C" void kernel_launch(void* const* d_in, const int* in_sizes, int n_in,
                              void* d_out, int out_size, void* d_ws, size_t ws_size,
                              hipStream_t stream) {
    const float* feat    = (const float*)d_in[0];
    const float* centers = (const float*)d_in[1];
    const float* textg   = (const float*)d_in[2];
    const float* w1      = (const float*)d_in[3];
    const float* b1      = (const float*)d_in[4];
    const float* w2      = (const float*)d_in[5];
    const float* b2      = (const float*)d_in[6];
    const float* wg      = (const float*)d_in[7];
    const float* bg      = (const float*)d_in[8];
    const float* wtb     = (const float*)d_in[9];
    const float* btb     = (const float*)d_in[10];
    const float* we1     = (const float*)d_in[11];
    const float* be1     = (const float*)d_in[12];
    const float* we2     = (const float*)d_in[13];
    const float* be2     = (const float*)d_in[14];
    const float* wm      = (const float*)d_in[15];
    const float* bm      = (const float*)d_in[16];
    const float* wo      = (const float*)d_in[17];
    const float* bo      = (const float*)d_in[18];
    const float* gamma   = (const float*)d_in[19];
    const float* beta    = (const float*)d_in[20];

    char* ws = (char*)d_ws;
    size_t off = 0;
    int* knn     = (int*)(ws + off);   off += (size_t)BB * NPT * KNN * 4;   // 1 MB
    float* gate  = (float*)(ws + off); off += (size_t)BB * H * 4;           // 64 KB
    float* tbias = (float*)(ws + off); off += (size_t)BB * H * 4;           // 64 KB
    float* MSG   = (float*)(ws + off); off += (size_t)BB * NPT * H * 4;     // 16 MB
    float* ctxG  = (float*)(ws + off); off += (size_t)BB * NPT * H * 4;     // 16 MB
    u16* w2t     = (u16*)(ws + off);   off += (size_t)256 * 256 * 2;        // 128 KB
    u16* we1t    = (u16*)(ws + off);   off += (size_t)128 * 256 * 2;        // 64 KB
    u16* wmt     = (u16*)(ws + off);   off += (size_t)256 * 256 * 2;        // 128 KB
    u16* wot     = (u16*)(ws + off);   off += (size_t)256 * 512 * 2;        // 256 KB

    prep_kernel<<<1152, 256, 0, stream>>>(w2, we1, wm, wo, w2t, we1t, wmt, wot);
    knn_kernel<<<256, 256, 0, stream>>>(centers, knn);
    gate_kernel<<<BB, 512, 0, stream>>>(textg, wg, bg, wtb, btb, gate, tbias);
    msg_mfma<<<BB * NPT / 64, 256, 0, stream>>>(feat, wmt, bm, MSG);
    edge_mfma<<<BB * NPT / 4, 256, 0, stream>>>(feat, centers, w1, b1, w2t, b2,
                                                we1t, be1, we2, be2, knn, gate, tbias,
                                                MSG, ctxG);
    out_mfma<<<BB * NPT / 32, 256, 0, stream>>>(feat, ctxG, wot, bo, gamma, beta,
                                                (float*)d_out);
}

// Round 6
// 353.951 us; speedup vs baseline: 3.7173x; 1.0338x over previous
//
#include <hip/hip_runtime.h>

#define H 256
#define KNN 16
#define NPT 256
#define BB 64

typedef unsigned short u16;
typedef unsigned int u32;
typedef __attribute__((ext_vector_type(8))) short shortx8;
typedef __attribute__((ext_vector_type(4))) float floatx4;

__device__ __forceinline__ u16 f2b(float f) {
    u32 u = __float_as_uint(f);
    u32 r = (u + 0x7fffu + ((u >> 16) & 1u)) >> 16;  // RNE
    return (u16)r;
}

// tanh via hw exp2: 1 - 2/(exp2(x*2log2e)+1). |err| ~1e-6, saturates correctly.
__device__ __forceinline__ float fast_tanh(float x) {
    float e = __builtin_amdgcn_exp2f(x * 2.88539008177793f);
    return 1.0f - 2.0f * __builtin_amdgcn_rcpf(e + 1.0f);
}

// ---------------------------------------------------------------------------
// K0: weight prep — bf16 transposed copies [n][k] for MFMA B-fragments.
// w1t is 256x32: K padded 4->32, k=4 holds b1 (bias lane), k>4 zero.
// ---------------------------------------------------------------------------
__global__ __launch_bounds__(256) void prep_kernel(
    const float* __restrict__ w2, const float* __restrict__ we1,
    const float* __restrict__ wm, const float* __restrict__ wo,
    const float* __restrict__ w1, const float* __restrict__ b1,
    u16* __restrict__ w2t, u16* __restrict__ we1t,
    u16* __restrict__ wmt, u16* __restrict__ wot, u16* __restrict__ w1t) {
    int tid = blockIdx.x * 256 + threadIdx.x;
    if (tid < 65536) {                       // w2t: 256 x 256
        int n = tid >> 8, k = tid & 255;
        w2t[tid] = f2b(w2[k * 256 + n]);
    } else if (tid < 98304) {                // we1t: 128 x 256
        int t = tid - 65536;
        int n = t >> 8, k = t & 255;
        we1t[t] = f2b(we1[k * 128 + n]);
    } else if (tid < 163840) {               // wmt: 256 x 256
        int t = tid - 98304;
        int n = t >> 8, k = t & 255;
        wmt[t] = f2b(wm[k * 256 + n]);
    } else if (tid < 294912) {               // wot: 256 x 512
        int t = tid - 163840;
        int n = t >> 9, k = t & 511;
        wot[t] = f2b(wo[k * 256 + n]);
    } else {                                 // w1t: 256 x 32
        int t = tid - 294912;
        int n = t >> 5, k = t & 31;
        float v = (k < 4) ? w1[k * 256 + n] : (k == 4 ? b1[n] : 0.0f);
        w1t[t] = f2b(v);
    }
}

// ---------------------------------------------------------------------------
// K1: exact KNN k=16, stable (d, idx)-lexicographic == jax.lax.top_k(-dist).
// 256 blocks: block = (batch, quarter of points). 4 scanner-waves per point
// group; wave s scans m in [s*64, s*64+64); wave 0 merges.
// ---------------------------------------------------------------------------
__global__ __launch_bounds__(256) void knn_kernel(const float* __restrict__ centers,
                                                  int* __restrict__ knn) {
    __shared__ float cx[NPT], cy[NPT], cz[NPT], sq[NPT];
    __shared__ float dl[4][64][17];
    __shared__ int il[4][64][17];
    int blk = blockIdx.x;
    int b = blk >> 2, n0 = (blk & 3) * 64;
    int h = threadIdx.x;
    int s = h >> 6, pt = h & 63;
    {
        const float* cb = centers + (size_t)b * NPT * 3;
        float x = cb[h * 3 + 0], y = cb[h * 3 + 1], z = cb[h * 3 + 2];
        cx[h] = x; cy[h] = y; cz[h] = z;
        sq[h] = x * x + y * y + z * z;
    }
    __syncthreads();
    int n = n0 + pt;
    float x = cx[n], y = cy[n], z = cz[n], sn = sq[n];
    float bd[KNN];
    int bi[KNN];
#pragma unroll
    for (int j = 0; j < KNN; j++) { bd[j] = 1e30f; bi[j] = 0x7fffffff; }
    for (int mm = 0; mm < 64; mm++) {
        int m = s * 64 + mm;
        float dot = x * cx[m] + y * cy[m] + z * cz[m];
        float d2 = (sn + sq[m]) - 2.0f * dot;
        float d = sqrtf(fmaxf(d2, 0.0f));
        if (d < bd[KNN - 1]) {  // in-order scan + strict < == lexicographic
            bd[KNN - 1] = d; bi[KNN - 1] = m;
#pragma unroll
            for (int p = KNN - 1; p > 0; --p) {
                if (bd[p - 1] > bd[p]) {
                    float td = bd[p - 1]; bd[p - 1] = bd[p]; bd[p] = td;
                    int ti = bi[p - 1]; bi[p - 1] = bi[p]; bi[p] = ti;
                }
            }
        }
    }
#pragma unroll
    for (int j = 0; j < KNN; j++) { dl[s][pt][j] = bd[j]; il[s][pt][j] = bi[j]; }
    __syncthreads();
    if (s == 0) {
        float md[KNN];
        int mi[KNN];
#pragma unroll
        for (int j = 0; j < KNN; j++) { md[j] = dl[0][pt][j]; mi[j] = il[0][pt][j]; }
        for (int t = 1; t < 4; t++) {
            for (int j = 0; j < KNN; j++) {
                float d = dl[t][pt][j];
                int idx = il[t][pt][j];
                bool ins = (d < md[KNN - 1]) || (d == md[KNN - 1] && idx < mi[KNN - 1]);
                if (!ins) break;  // source list sorted lexicographically
                md[KNN - 1] = d; mi[KNN - 1] = idx;
#pragma unroll
                for (int p = KNN - 1; p > 0; --p) {
                    bool sw = (md[p - 1] > md[p]) ||
                              (md[p - 1] == md[p] && mi[p - 1] > mi[p]);
                    if (sw) {
                        float td = md[p - 1]; md[p - 1] = md[p]; md[p] = td;
                        int ti = mi[p - 1]; mi[p - 1] = mi[p]; mi[p] = ti;
                    }
                }
            }
        }
        int* kp = knn + (b * NPT + n0 + pt) * KNN;
#pragma unroll
        for (int j = 0; j < KNN; j++) kp[j] = mi[j];
    }
}

// ---------------------------------------------------------------------------
// K2: text gate / bias per batch. 512 threads: 0..255 gate, 256..511 tbias.
// ---------------------------------------------------------------------------
__global__ __launch_bounds__(512) void gate_kernel(const float* __restrict__ tg_g,
                                                   const float* __restrict__ wg,
                                                   const float* __restrict__ bg,
                                                   const float* __restrict__ wtb,
                                                   const float* __restrict__ btb,
                                                   float* __restrict__ gate,
                                                   float* __restrict__ tbias) {
    __shared__ float tg[H];
    int b = blockIdx.x, t = threadIdx.x;
    if (t < H) tg[t] = tg_g[b * H + t];
    __syncthreads();
    int h = t & 255;
    if (t < H) {
        float ag = bg[h];
#pragma unroll 4
        for (int i = 0; i < H; i++) ag += tg[i] * wg[i * H + h];
        gate[b * H + h] = 1.0f / (1.0f + expf(-ag));
    } else {
        float ab = btb[h];
#pragma unroll 4
        for (int i = 0; i < H; i++) ab += tg[i] * wtb[i * H + h];
        tbias[b * H + h] = ab;
    }
}

// ---------------------------------------------------------------------------
// K3: MSG = relu(feat @ Wm + bm), MFMA, 64 points/block (M=64, B reuse x4).
// ---------------------------------------------------------------------------
__global__ __launch_bounds__(256, 4) void msg_mfma(const float* __restrict__ feat,
                                                   const u16* __restrict__ wmt,
                                                   const float* __restrict__ bm,
                                                   float* __restrict__ MSG) {
    __shared__ __attribute__((aligned(16))) u16 A[64][264];
    int p0 = blockIdx.x * 64, h = threadIdx.x;
    int w = h >> 6, lane = h & 63, quad = lane >> 4, lq = lane & 15;
#pragma unroll 8
    for (int row = 0; row < 64; row++)
        A[row][h] = f2b(feat[(size_t)(p0 + row) * H + h]);
    __syncthreads();
    floatx4 acc[4][4];
#pragma unroll
    for (int rt = 0; rt < 4; rt++)
#pragma unroll
        for (int ct = 0; ct < 4; ct++) acc[rt][ct] = (floatx4){0, 0, 0, 0};
#pragma unroll 2
    for (int kt = 0; kt < 8; kt++) {
        shortx8 bf[4];
#pragma unroll
        for (int ct = 0; ct < 4; ct++)
            bf[ct] = *(const shortx8*)&wmt[(w * 64 + ct * 16 + lq) * 256 + kt * 32 + quad * 8];
#pragma unroll
        for (int rt = 0; rt < 4; rt++) {
            shortx8 a = *(const shortx8*)&A[rt * 16 + lq][kt * 32 + quad * 8];
#pragma unroll
            for (int ct = 0; ct < 4; ct++)
                acc[rt][ct] = __builtin_amdgcn_mfma_f32_16x16x32_bf16(a, bf[ct], acc[rt][ct], 0, 0, 0);
        }
    }
#pragma unroll
    for (int ct = 0; ct < 4; ct++) {
        int col = w * 64 + ct * 16 + lq;
        float bmc = bm[col];
#pragma unroll
        for (int rt = 0; rt < 4; rt++)
#pragma unroll
            for (int r = 0; r < 4; r++) {
                int row = rt * 16 + quad * 4 + r;
                MSG[(size_t)(p0 + row) * H + col] = fmaxf(acc[rt][ct][r] + bmc, 0.0f);
            }
    }
}

// ---------------------------------------------------------------------------
// K4: fused edge pipeline, 4 points/block (M=64 edges). g1 via MFMA with
// bias folded into K-slot 4. ~40 KB LDS -> 4 blocks/CU.
// ---------------------------------------------------------------------------
__global__ __launch_bounds__(256, 4) void edge_mfma(
    const float* __restrict__ feat, const float* __restrict__ centers,
    const u16* __restrict__ w1t,
    const u16* __restrict__ w2t, const float* __restrict__ b2v,
    const u16* __restrict__ we1t, const float* __restrict__ be1,
    const float* __restrict__ we2, const float* __restrict__ be2,
    const int* __restrict__ knn, const float* __restrict__ gateG,
    const float* __restrict__ tbiasG, const float* __restrict__ MSG,
    float* __restrict__ ctxG) {
    __shared__ __attribute__((aligned(16))) u16 A[64][264];  // g1 then edge_feat
    __shared__ float fnS[4][H];
    __shared__ __attribute__((aligned(16))) float geomS[64][4];
    __shared__ int nidxS[64];
    __shared__ float part[4][64];
    __shared__ float logitsS[64];
    __shared__ float alphaS[64];

    int bn0 = blockIdx.x * 4;
    int b = bn0 >> 8, n0 = bn0 & 255;
    int h = threadIdx.x;
    int w = h >> 6, lane = h & 63, quad = lane >> 4, lq = lane & 15;

    // phase 0: nidx + fn staging
    if (h < 64) nidxS[h] = knn[bn0 * KNN + h];
#pragma unroll
    for (int p = 0; p < 4; p++)
        fnS[p][h] = feat[(size_t)(bn0 + p) * H + h];
    // phase 1: geom per edge-row (h<64: point p=h>>4, neighbor j=h&15);
    // reads only own-thread nidxS[h] write from phase 0.
    if (h < 64) {
        int p = h >> 4;
        int m = nidxS[h];
        int n = n0 + p;
        const float* cb = centers + (size_t)b * NPT * 3;
        float rx = cb[m * 3 + 0] - cb[n * 3 + 0];
        float ry = cb[m * 3 + 1] - cb[n * 3 + 1];
        float rz = cb[m * 3 + 2] - cb[n * 3 + 2];
        float dist = sqrtf(rx * rx + ry * ry + rz * rz) + 1e-6f;
        geomS[h][0] = rx; geomS[h][1] = ry; geomS[h][2] = rz;
        geomS[h][3] = log1pf(dist);
    }
    __syncthreads();

    // phase 2: g1[64][256] = relu(geomP @ W1t) via MFMA (K=32 padded, k=4 bias)
    {
        shortx8 bw1[4];
#pragma unroll
        for (int ct = 0; ct < 4; ct++)
            bw1[ct] = *(const shortx8*)&w1t[(w * 64 + ct * 16 + lq) * 32 + quad * 8];
#pragma unroll
        for (int rt = 0; rt < 4; rt++) {
            shortx8 ag = {0, 0, 0, 0, 0, 0, 0, 0};
            if (quad == 0) {
                float4 g = *(const float4*)&geomS[rt * 16 + lq][0];
                ag[0] = (short)f2b(g.x);
                ag[1] = (short)f2b(g.y);
                ag[2] = (short)f2b(g.z);
                ag[3] = (short)f2b(g.w);
                ag[4] = (short)0x3F80;  // 1.0 -> multiplies bias row of w1t
            }
#pragma unroll
            for (int ct = 0; ct < 4; ct++) {
                floatx4 accg = __builtin_amdgcn_mfma_f32_16x16x32_bf16(
                    ag, bw1[ct], (floatx4){0, 0, 0, 0}, 0, 0, 0);
#pragma unroll
                for (int r = 0; r < 4; r++)
                    A[rt * 16 + quad * 4 + r][w * 64 + ct * 16 + lq] =
                        f2b(fmaxf(accg[r], 0.0f));
            }
        }
    }
    __syncthreads();

    // GEMM1: C1[64][256] = g1 @ W2
    floatx4 acc[4][4];
#pragma unroll
    for (int rt = 0; rt < 4; rt++)
#pragma unroll
        for (int ct = 0; ct < 4; ct++) acc[rt][ct] = (floatx4){0, 0, 0, 0};
#pragma unroll 2
    for (int kt = 0; kt < 8; kt++) {
        shortx8 bf[4];
#pragma unroll
        for (int ct = 0; ct < 4; ct++)
            bf[ct] = *(const shortx8*)&w2t[(w * 64 + ct * 16 + lq) * 256 + kt * 32 + quad * 8];
#pragma unroll
        for (int rt = 0; rt < 4; rt++) {
            shortx8 a = *(const shortx8*)&A[rt * 16 + lq][kt * 32 + quad * 8];
#pragma unroll
            for (int ct = 0; ct < 4; ct++)
                acc[rt][ct] = __builtin_amdgcn_mfma_f32_16x16x32_bf16(a, bf[ct], acc[rt][ct], 0, 0, 0);
        }
    }
    __syncthreads();  // all g1 reads done

    // epilogue1: edge_feat = tanh(fn + fnb + relu(C1+b2)*gate + tbias) -> A
#pragma unroll
    for (int ct = 0; ct < 4; ct++) {
        int col = w * 64 + ct * 16 + lq;
        float b2c = b2v[col];
        float gc = gateG[b * H + col];
        float tc = tbiasG[b * H + col];
#pragma unroll
        for (int rt = 0; rt < 4; rt++) {
            float fnc = fnS[rt][col];
#pragma unroll
            for (int r = 0; r < 4; r++) {
                int row = rt * 16 + quad * 4 + r;
                float fb = feat[((size_t)b * NPT + nidxS[row]) * H + col];
                float emb = fmaxf(acc[rt][ct][r] + b2c, 0.0f);
                float ef = fast_tanh(fnc + fb + emb * gc + tc);
                A[row][col] = f2b(ef);
            }
        }
    }
    __syncthreads();

    // GEMM2: C2[64][128] = edge_feat @ We1
    floatx4 acc2[4][2];
#pragma unroll
    for (int rt = 0; rt < 4; rt++)
#pragma unroll
        for (int c2 = 0; c2 < 2; c2++) acc2[rt][c2] = (floatx4){0, 0, 0, 0};
#pragma unroll 2
    for (int kt = 0; kt < 8; kt++) {
        shortx8 bf[2];
#pragma unroll
        for (int c2 = 0; c2 < 2; c2++)
            bf[c2] = *(const shortx8*)&we1t[(w * 32 + c2 * 16 + lq) * 256 + kt * 32 + quad * 8];
#pragma unroll
        for (int rt = 0; rt < 4; rt++) {
            shortx8 a = *(const shortx8*)&A[rt * 16 + lq][kt * 32 + quad * 8];
#pragma unroll
            for (int c2 = 0; c2 < 2; c2++)
                acc2[rt][c2] = __builtin_amdgcn_mfma_f32_16x16x32_bf16(a, bf[c2], acc2[rt][c2], 0, 0, 0);
        }
    }

    // logits partials
    float pl[4][4];
#pragma unroll
    for (int rt = 0; rt < 4; rt++)
#pragma unroll
        for (int r = 0; r < 4; r++) pl[rt][r] = 0.0f;
#pragma unroll
    for (int c2 = 0; c2 < 2; c2++) {
        int col = w * 32 + c2 * 16 + lq;
        float be1c = be1[col], w2c = we2[col];
#pragma unroll
        for (int rt = 0; rt < 4; rt++)
#pragma unroll
            for (int r = 0; r < 4; r++)
                pl[rt][r] += fmaxf(acc2[rt][c2][r] + be1c, 0.0f) * w2c;
    }
#pragma unroll
    for (int d = 1; d < 16; d <<= 1)
#pragma unroll
        for (int rt = 0; rt < 4; rt++)
#pragma unroll
            for (int r = 0; r < 4; r++) pl[rt][r] += __shfl_xor(pl[rt][r], d, 16);
    if (lq == 0) {
#pragma unroll
        for (int rt = 0; rt < 4; rt++)
#pragma unroll
            for (int r = 0; r < 4; r++)
                part[w][rt * 16 + quad * 4 + r] = pl[rt][r];
    }
    __syncthreads();
    if (h < 64)
        logitsS[h] = part[0][h] + part[1][h] + part[2][h] + part[3][h] + be2[0];
    __syncthreads();
    if (h < 64) {
        int base = (h >> 4) * 16;
        float mx = -1e30f;
#pragma unroll
        for (int j = 0; j < KNN; j++) mx = fmaxf(mx, logitsS[base + j]);
        float sum = 0.0f;
#pragma unroll
        for (int j = 0; j < KNN; j++) sum += expf(logitsS[base + j] - mx);
        alphaS[h] = expf(logitsS[h] - mx) / sum;
    }
    __syncthreads();

    // ctx: thread -> (point p, 4 consecutive cols); float4 gather over 16 nbrs
    {
        int p = h >> 6, cg = (h & 63) * 4;
        float4 c = {0, 0, 0, 0};
#pragma unroll
        for (int j = 0; j < KNN; j++) {
            float al = alphaS[p * 16 + j];
            float4 m = *(const float4*)&MSG[((size_t)b * NPT + nidxS[p * 16 + j]) * H + cg];
            c.x += al * m.x; c.y += al * m.y; c.z += al * m.z; c.w += al * m.w;
        }
        *(float4*)&ctxG[(size_t)(bn0 + p) * H + cg] = c;
    }
}

// ---------------------------------------------------------------------------
// K5: out = LN(feat + relu([feat|ctx] @ Wo + bo)), MFMA, 32 points/block.
// ---------------------------------------------------------------------------
__global__ __launch_bounds__(256, 4) void out_mfma(const float* __restrict__ feat,
                                                   const float* __restrict__ ctxG,
                                                   const u16* __restrict__ wot,
                                                   const float* __restrict__ bo,
                                                   const float* __restrict__ gamma,
                                                   const float* __restrict__ beta,
                                                   float* __restrict__ out) {
    __shared__ __attribute__((aligned(16))) u16 A[32][520];
    __shared__ float redS[4][32], redS2[4][32];
    int p0 = blockIdx.x * 32, h = threadIdx.x;
    int w = h >> 6, lane = h & 63, quad = lane >> 4, lq = lane & 15;
#pragma unroll 8
    for (int row = 0; row < 32; row++) {
        A[row][h]       = f2b(feat[(size_t)(p0 + row) * H + h]);
        A[row][256 + h] = f2b(ctxG[(size_t)(p0 + row) * H + h]);
    }
    __syncthreads();
    floatx4 acc[2][4];
#pragma unroll
    for (int rt = 0; rt < 2; rt++)
#pragma unroll
        for (int ct = 0; ct < 4; ct++) acc[rt][ct] = (floatx4){0, 0, 0, 0};
#pragma unroll 2
    for (int kt = 0; kt < 16; kt++) {
        shortx8 bf[4];
#pragma unroll
        for (int ct = 0; ct < 4; ct++)
            bf[ct] = *(const shortx8*)&wot[(w * 64 + ct * 16 + lq) * 512 + kt * 32 + quad * 8];
#pragma unroll
        for (int rt = 0; rt < 2; rt++) {
            shortx8 a = *(const shortx8*)&A[rt * 16 + lq][kt * 32 + quad * 8];
#pragma unroll
            for (int ct = 0; ct < 4; ct++)
                acc[rt][ct] = __builtin_amdgcn_mfma_f32_16x16x32_bf16(a, bf[ct], acc[rt][ct], 0, 0, 0);
        }
    }
    float x[2][4][4];
    float sm[2][4], sq2[2][4];
#pragma unroll
    for (int rt = 0; rt < 2; rt++)
#pragma unroll
        for (int r = 0; r < 4; r++) { sm[rt][r] = 0.0f; sq2[rt][r] = 0.0f; }
#pragma unroll
    for (int rt = 0; rt < 2; rt++)
#pragma unroll
        for (int ct = 0; ct < 4; ct++) {
            int col = w * 64 + ct * 16 + lq;
            float boc = bo[col];
#pragma unroll
            for (int r = 0; r < 4; r++) {
                int row = rt * 16 + quad * 4 + r;
                float xx = feat[(size_t)(p0 + row) * H + col] +
                           fmaxf(acc[rt][ct][r] + boc, 0.0f);
                x[rt][ct][r] = xx;
                sm[rt][r] += xx;
                sq2[rt][r] += xx * xx;
            }
        }
#pragma unroll
    for (int d = 1; d < 16; d <<= 1)
#pragma unroll
        for (int rt = 0; rt < 2; rt++)
#pragma unroll
            for (int r = 0; r < 4; r++) {
                sm[rt][r] += __shfl_xor(sm[rt][r], d, 16);
                sq2[rt][r] += __shfl_xor(sq2[rt][r], d, 16);
            }
    if (lq == 0) {
#pragma unroll
        for (int rt = 0; rt < 2; rt++)
#pragma unroll
            for (int r = 0; r < 4; r++) {
                redS[w][rt * 16 + quad * 4 + r] = sm[rt][r];
                redS2[w][rt * 16 + quad * 4 + r] = sq2[rt][r];
            }
    }
    __syncthreads();
#pragma unroll
    for (int rt = 0; rt < 2; rt++)
#pragma unroll
        for (int r = 0; r < 4; r++) {
            int row = rt * 16 + quad * 4 + r;
            float s1 = redS[0][row] + redS[1][row] + redS[2][row] + redS[3][row];
            float s2 = redS2[0][row] + redS2[1][row] + redS2[2][row] + redS2[3][row];
            float mu = s1 * (1.0f / H);
            float var = s2 * (1.0f / H) - mu * mu;
            float inv = rsqrtf(fmaxf(var, 0.0f) + 1e-5f);
#pragma unroll
            for (int ct = 0; ct < 4; ct++) {
                int col = w * 64 + ct * 16 + lq;
                out[(size_t)(p0 + row) * H + col] =
                    (x[rt][ct][r] - mu) * inv * gamma[col] + beta[col];
            }
        }
}

// ---------------------------------------------------------------------------
extern "C" void kernel_launch(void* const* d_in, const int* in_sizes, int n_in,
                              void* d_out, int out_size, void* d_ws, size_t ws_size,
                              hipStream_t stream) {
    const float* feat    = (const float*)d_in[0];
    const float* centers = (const float*)d_in[1];
    const float* textg   = (const float*)d_in[2];
    const float* w1      = (const float*)d_in[3];
    const float* b1      = (const float*)d_in[4];
    const float* w2      = (const float*)d_in[5];
    const float* b2      = (const float*)d_in[6];
    const float* wg      = (const float*)d_in[7];
    const float* bg      = (const float*)d_in[8];
    const float* wtb     = (const float*)d_in[9];
    const float* btb     = (const float*)d_in[10];
    const float* we1     = (const float*)d_in[11];
    const float* be1     = (const float*)d_in[12];
    const float* we2     = (const float*)d_in[13];
    const float* be2     = (const float*)d_in[14];
    const float* wm      = (const float*)d_in[15];
    const float* bm      = (const float*)d_in[16];
    const float* wo      = (const float*)d_in[17];
    const float* bo      = (const float*)d_in[18];
    const float* gamma   = (const float*)d_in[19];
    const float* beta    = (const float*)d_in[20];

    char* ws = (char*)d_ws;
    size_t off = 0;
    int* knn     = (int*)(ws + off);   off += (size_t)BB * NPT * KNN * 4;   // 1 MB
    float* gate  = (float*)(ws + off); off += (size_t)BB * H * 4;           // 64 KB
    float* tbias = (float*)(ws + off); off += (size_t)BB * H * 4;           // 64 KB
    float* MSG   = (float*)(ws + off); off += (size_t)BB * NPT * H * 4;     // 16 MB
    float* ctxG  = (float*)(ws + off); off += (size_t)BB * NPT * H * 4;     // 16 MB
    u16* w2t     = (u16*)(ws + off);   off += (size_t)256 * 256 * 2;        // 128 KB
    u16* we1t    = (u16*)(ws + off);   off += (size_t)128 * 256 * 2;        // 64 KB
    u16* wmt     = (u16*)(ws + off);   off += (size_t)256 * 256 * 2;        // 128 KB
    u16* wot     = (u16*)(ws + off);   off += (size_t)256 * 512 * 2;        // 256 KB
    u16* w1t     = (u16*)(ws + off);   off += (size_t)256 * 32 * 2;         // 16 KB

    prep_kernel<<<1184, 256, 0, stream>>>(w2, we1, wm, wo, w1, b1,
                                          w2t, we1t, wmt, wot, w1t);
    knn_kernel<<<256, 256, 0, stream>>>(centers, knn);
    gate_kernel<<<BB, 512, 0, stream>>>(textg, wg, bg, wtb, btb, gate, tbias);
    msg_mfma<<<BB * NPT / 64, 256, 0, stream>>>(feat, wmt, bm, MSG);
    edge_mfma<<<BB * NPT / 4, 256, 0, stream>>>(feat, centers, w1t, w2t, b2,
                                                we1t, be1, we2, be2, knn, gate, tbias,
                                                MSG, ctxG);
    out_mfma<<<BB * NPT / 32, 256, 0, stream>>>(feat, ctxG, wot, bo, gamma, beta,
                                                (float*)d_out);
}

// Round 7
// 347.259 us; speedup vs baseline: 3.7889x; 1.0193x over previous
//
#include <hip/hip_runtime.h>

#define H 256
#define KNN 16
#define NPT 256
#define BB 64

typedef unsigned short u16;
typedef unsigned int u32;
typedef __attribute__((ext_vector_type(8))) short shortx8;
typedef __attribute__((ext_vector_type(4))) float floatx4;

__device__ __forceinline__ u16 f2b(float f) {
    u32 u = __float_as_uint(f);
    u32 r = (u + 0x7fffu + ((u >> 16) & 1u)) >> 16;  // RNE
    return (u16)r;
}
__device__ __forceinline__ float b2f(u16 u) {
    return __uint_as_float(((u32)u) << 16);
}

// tanh via hw exp2: 1 - 2/(exp2(x*2log2e)+1). |err| ~1e-6, saturates correctly.
__device__ __forceinline__ float fast_tanh(float x) {
    float e = __builtin_amdgcn_exp2f(x * 2.88539008177793f);
    return 1.0f - 2.0f * __builtin_amdgcn_rcpf(e + 1.0f);
}

// ---------------------------------------------------------------------------
// K0: prep — bf16 transposed weights [n][k] for MFMA B-fragments, plus
// featB (bf16 copy of feat). Blocks [0,1184): weights; [1184,5280): featB.
// w1t is 256x32: K padded 4->32, k=4 holds b1 (bias lane), k>4 zero.
// ---------------------------------------------------------------------------
__global__ __launch_bounds__(256) void prep_kernel(
    const float* __restrict__ feat,
    const float* __restrict__ w2, const float* __restrict__ we1,
    const float* __restrict__ wm, const float* __restrict__ wo,
    const float* __restrict__ w1, const float* __restrict__ b1,
    u16* __restrict__ w2t, u16* __restrict__ we1t,
    u16* __restrict__ wmt, u16* __restrict__ wot, u16* __restrict__ w1t,
    u16* __restrict__ featB) {
    int blk = blockIdx.x;
    if (blk < 1184) {
        int tid = blk * 256 + threadIdx.x;
        if (tid < 65536) {                       // w2t: 256 x 256
            int n = tid >> 8, k = tid & 255;
            w2t[tid] = f2b(w2[k * 256 + n]);
        } else if (tid < 98304) {                // we1t: 128 x 256
            int t = tid - 65536;
            int n = t >> 8, k = t & 255;
            we1t[t] = f2b(we1[k * 128 + n]);
        } else if (tid < 163840) {               // wmt: 256 x 256
            int t = tid - 98304;
            int n = t >> 8, k = t & 255;
            wmt[t] = f2b(wm[k * 256 + n]);
        } else if (tid < 294912) {               // wot: 256 x 512
            int t = tid - 163840;
            int n = t >> 9, k = t & 511;
            wot[t] = f2b(wo[k * 256 + n]);
        } else {                                 // w1t: 256 x 32
            int t = tid - 294912;
            int n = t >> 5, k = t & 31;
            float v = (k < 4) ? w1[k * 256 + n] : (k == 4 ? b1[n] : 0.0f);
            w1t[t] = f2b(v);
        }
        return;
    }
    // featB: 4 elements per thread, 4096 blocks x 256 threads x 4 = 4.19M
    int e = (blk - 1184) * 256 + threadIdx.x;
    float4 f = *(const float4*)&feat[(size_t)e * 4];
    uint2 st;
    st.x = (u32)f2b(f.x) | ((u32)f2b(f.y) << 16);
    st.y = (u32)f2b(f.z) | ((u32)f2b(f.w) << 16);
    *(uint2*)&featB[(size_t)e * 4] = st;
}

// ---------------------------------------------------------------------------
// K1: exact KNN k=16, stable (d, idx)-lexicographic == jax.lax.top_k(-dist).
// 256 blocks: block = (batch, quarter of points). 4 scanner-waves per point
// group; wave s scans m in [s*64, s*64+64); wave 0 merges.
// ---------------------------------------------------------------------------
__global__ __launch_bounds__(256) void knn_kernel(const float* __restrict__ centers,
                                                  int* __restrict__ knn) {
    __shared__ float cx[NPT], cy[NPT], cz[NPT], sq[NPT];
    __shared__ float dl[4][64][17];
    __shared__ int il[4][64][17];
    int blk = blockIdx.x;
    int b = blk >> 2, n0 = (blk & 3) * 64;
    int h = threadIdx.x;
    int s = h >> 6, pt = h & 63;
    {
        const float* cb = centers + (size_t)b * NPT * 3;
        float x = cb[h * 3 + 0], y = cb[h * 3 + 1], z = cb[h * 3 + 2];
        cx[h] = x; cy[h] = y; cz[h] = z;
        sq[h] = x * x + y * y + z * z;
    }
    __syncthreads();
    int n = n0 + pt;
    float x = cx[n], y = cy[n], z = cz[n], sn = sq[n];
    float bd[KNN];
    int bi[KNN];
#pragma unroll
    for (int j = 0; j < KNN; j++) { bd[j] = 1e30f; bi[j] = 0x7fffffff; }
    for (int mm = 0; mm < 64; mm++) {
        int m = s * 64 + mm;
        float dot = x * cx[m] + y * cy[m] + z * cz[m];
        float d2 = (sn + sq[m]) - 2.0f * dot;
        float d = sqrtf(fmaxf(d2, 0.0f));
        if (d < bd[KNN - 1]) {  // in-order scan + strict < == lexicographic
            bd[KNN - 1] = d; bi[KNN - 1] = m;
#pragma unroll
            for (int p = KNN - 1; p > 0; --p) {
                if (bd[p - 1] > bd[p]) {
                    float td = bd[p - 1]; bd[p - 1] = bd[p]; bd[p] = td;
                    int ti = bi[p - 1]; bi[p - 1] = bi[p]; bi[p] = ti;
                }
            }
        }
    }
#pragma unroll
    for (int j = 0; j < KNN; j++) { dl[s][pt][j] = bd[j]; il[s][pt][j] = bi[j]; }
    __syncthreads();
    if (s == 0) {
        float md[KNN];
        int mi[KNN];
#pragma unroll
        for (int j = 0; j < KNN; j++) { md[j] = dl[0][pt][j]; mi[j] = il[0][pt][j]; }
        for (int t = 1; t < 4; t++) {
            for (int j = 0; j < KNN; j++) {
                float d = dl[t][pt][j];
                int idx = il[t][pt][j];
                bool ins = (d < md[KNN - 1]) || (d == md[KNN - 1] && idx < mi[KNN - 1]);
                if (!ins) break;  // source list sorted lexicographically
                md[KNN - 1] = d; mi[KNN - 1] = idx;
#pragma unroll
                for (int p = KNN - 1; p > 0; --p) {
                    bool sw = (md[p - 1] > md[p]) ||
                              (md[p - 1] == md[p] && mi[p - 1] > mi[p]);
                    if (sw) {
                        float td = md[p - 1]; md[p - 1] = md[p]; md[p] = td;
                        int ti = mi[p - 1]; mi[p - 1] = mi[p]; mi[p] = ti;
                    }
                }
            }
        }
        int* kp = knn + (b * NPT + n0 + pt) * KNN;
#pragma unroll
        for (int j = 0; j < KNN; j++) kp[j] = mi[j];
    }
}

// ---------------------------------------------------------------------------
// K2: text gate / bias per batch. 512 threads: 0..255 gate, 256..511 tbias.
// ---------------------------------------------------------------------------
__global__ __launch_bounds__(512) void gate_kernel(const float* __restrict__ tg_g,
                                                   const float* __restrict__ wg,
                                                   const float* __restrict__ bg,
                                                   const float* __restrict__ wtb,
                                                   const float* __restrict__ btb,
                                                   float* __restrict__ gate,
                                                   float* __restrict__ tbias) {
    __shared__ float tg[H];
    int b = blockIdx.x, t = threadIdx.x;
    if (t < H) tg[t] = tg_g[b * H + t];
    __syncthreads();
    int h = t & 255;
    if (t < H) {
        float ag = bg[h];
#pragma unroll 4
        for (int i = 0; i < H; i++) ag += tg[i] * wg[i * H + h];
        gate[b * H + h] = 1.0f / (1.0f + expf(-ag));
    } else {
        float ab = btb[h];
#pragma unroll 4
        for (int i = 0; i < H; i++) ab += tg[i] * wtb[i * H + h];
        tbias[b * H + h] = ab;
    }
}

// ---------------------------------------------------------------------------
// K3: MSGB = bf16(relu(feat @ Wm + bm)), MFMA, 64 points/block.
// A staged directly from featB (no cvt).
// ---------------------------------------------------------------------------
__global__ __launch_bounds__(256, 4) void msg_mfma(const u16* __restrict__ featB,
                                                   const u16* __restrict__ wmt,
                                                   const float* __restrict__ bm,
                                                   u16* __restrict__ MSGB) {
    __shared__ __attribute__((aligned(16))) u16 A[64][264];
    int p0 = blockIdx.x * 64, h = threadIdx.x;
    int w = h >> 6, lane = h & 63, quad = lane >> 4, lq = lane & 15;
#pragma unroll 8
    for (int row = 0; row < 64; row++)
        A[row][h] = featB[(size_t)(p0 + row) * H + h];
    __syncthreads();
    floatx4 acc[4][4];
#pragma unroll
    for (int rt = 0; rt < 4; rt++)
#pragma unroll
        for (int ct = 0; ct < 4; ct++) acc[rt][ct] = (floatx4){0, 0, 0, 0};
#pragma unroll 2
    for (int kt = 0; kt < 8; kt++) {
        shortx8 bf[4];
#pragma unroll
        for (int ct = 0; ct < 4; ct++)
            bf[ct] = *(const shortx8*)&wmt[(w * 64 + ct * 16 + lq) * 256 + kt * 32 + quad * 8];
#pragma unroll
        for (int rt = 0; rt < 4; rt++) {
            shortx8 a = *(const shortx8*)&A[rt * 16 + lq][kt * 32 + quad * 8];
#pragma unroll
            for (int ct = 0; ct < 4; ct++)
                acc[rt][ct] = __builtin_amdgcn_mfma_f32_16x16x32_bf16(a, bf[ct], acc[rt][ct], 0, 0, 0);
        }
    }
#pragma unroll
    for (int ct = 0; ct < 4; ct++) {
        int col = w * 64 + ct * 16 + lq;
        float bmc = bm[col];
#pragma unroll
        for (int rt = 0; rt < 4; rt++)
#pragma unroll
            for (int r = 0; r < 4; r++) {
                int row = rt * 16 + quad * 4 + r;
                MSGB[(size_t)(p0 + row) * H + col] = f2b(fmaxf(acc[rt][ct][r] + bmc, 0.0f));
            }
    }
}

// ---------------------------------------------------------------------------
// K4: fused edge pipeline, 4 points/block (M=64 edges). g1 via MFMA with
// bias folded into K-slot 4. fb gather + MSG gather + ctx write in bf16.
// ---------------------------------------------------------------------------
__global__ __launch_bounds__(256, 4) void edge_mfma(
    const float* __restrict__ feat, const u16* __restrict__ featB,
    const float* __restrict__ centers,
    const u16* __restrict__ w1t,
    const u16* __restrict__ w2t, const float* __restrict__ b2v,
    const u16* __restrict__ we1t, const float* __restrict__ be1,
    const float* __restrict__ we2, const float* __restrict__ be2,
    const int* __restrict__ knn, const float* __restrict__ gateG,
    const float* __restrict__ tbiasG, const u16* __restrict__ MSGB,
    u16* __restrict__ ctxB) {
    __shared__ __attribute__((aligned(16))) u16 A[64][264];  // g1 then edge_feat
    __shared__ float fnS[4][H];
    __shared__ __attribute__((aligned(16))) float geomS[64][4];
    __shared__ int nidxS[64];
    __shared__ float part[4][64];
    __shared__ float logitsS[64];
    __shared__ float alphaS[64];

    int bn0 = blockIdx.x * 4;
    int b = bn0 >> 8, n0 = bn0 & 255;
    int h = threadIdx.x;
    int w = h >> 6, lane = h & 63, quad = lane >> 4, lq = lane & 15;

    // phase 0: nidx + fn staging
    if (h < 64) nidxS[h] = knn[bn0 * KNN + h];
#pragma unroll
    for (int p = 0; p < 4; p++)
        fnS[p][h] = feat[(size_t)(bn0 + p) * H + h];
    // phase 1: geom per edge-row (h<64: point p=h>>4, neighbor j=h&15);
    // reads only own-thread nidxS[h] write from phase 0.
    if (h < 64) {
        int p = h >> 4;
        int m = nidxS[h];
        int n = n0 + p;
        const float* cb = centers + (size_t)b * NPT * 3;
        float rx = cb[m * 3 + 0] - cb[n * 3 + 0];
        float ry = cb[m * 3 + 1] - cb[n * 3 + 1];
        float rz = cb[m * 3 + 2] - cb[n * 3 + 2];
        float dist = sqrtf(rx * rx + ry * ry + rz * rz) + 1e-6f;
        geomS[h][0] = rx; geomS[h][1] = ry; geomS[h][2] = rz;
        geomS[h][3] = log1pf(dist);
    }
    __syncthreads();

    // phase 2: g1[64][256] = relu(geomP @ W1t) via MFMA (K=32 padded, k=4 bias)
    {
        shortx8 bw1[4];
#pragma unroll
        for (int ct = 0; ct < 4; ct++)
            bw1[ct] = *(const shortx8*)&w1t[(w * 64 + ct * 16 + lq) * 32 + quad * 8];
#pragma unroll
        for (int rt = 0; rt < 4; rt++) {
            shortx8 ag = {0, 0, 0, 0, 0, 0, 0, 0};
            if (quad == 0) {
                float4 g = *(const float4*)&geomS[rt * 16 + lq][0];
                ag[0] = (short)f2b(g.x);
                ag[1] = (short)f2b(g.y);
                ag[2] = (short)f2b(g.z);
                ag[3] = (short)f2b(g.w);
                ag[4] = (short)0x3F80;  // 1.0 -> multiplies bias row of w1t
            }
#pragma unroll
            for (int ct = 0; ct < 4; ct++) {
                floatx4 accg = __builtin_amdgcn_mfma_f32_16x16x32_bf16(
                    ag, bw1[ct], (floatx4){0, 0, 0, 0}, 0, 0, 0);
#pragma unroll
                for (int r = 0; r < 4; r++)
                    A[rt * 16 + quad * 4 + r][w * 64 + ct * 16 + lq] =
                        f2b(fmaxf(accg[r], 0.0f));
            }
        }
    }
    __syncthreads();

    // GEMM1: C1[64][256] = g1 @ W2
    floatx4 acc[4][4];
#pragma unroll
    for (int rt = 0; rt < 4; rt++)
#pragma unroll
        for (int ct = 0; ct < 4; ct++) acc[rt][ct] = (floatx4){0, 0, 0, 0};
#pragma unroll 2
    for (int kt = 0; kt < 8; kt++) {
        shortx8 bf[4];
#pragma unroll
        for (int ct = 0; ct < 4; ct++)
            bf[ct] = *(const shortx8*)&w2t[(w * 64 + ct * 16 + lq) * 256 + kt * 32 + quad * 8];
#pragma unroll
        for (int rt = 0; rt < 4; rt++) {
            shortx8 a = *(const shortx8*)&A[rt * 16 + lq][kt * 32 + quad * 8];
#pragma unroll
            for (int ct = 0; ct < 4; ct++)
                acc[rt][ct] = __builtin_amdgcn_mfma_f32_16x16x32_bf16(a, bf[ct], acc[rt][ct], 0, 0, 0);
        }
    }
    __syncthreads();  // all g1 reads done

    // epilogue1: edge_feat = tanh(fn + fnb + relu(C1+b2)*gate + tbias) -> A
#pragma unroll
    for (int ct = 0; ct < 4; ct++) {
        int col = w * 64 + ct * 16 + lq;
        float b2c = b2v[col];
        float gc = gateG[b * H + col];
        float tc = tbiasG[b * H + col];
#pragma unroll
        for (int rt = 0; rt < 4; rt++) {
            float fnc = fnS[rt][col];
#pragma unroll
            for (int r = 0; r < 4; r++) {
                int row = rt * 16 + quad * 4 + r;
                float fb = b2f(featB[((size_t)b * NPT + nidxS[row]) * H + col]);
                float emb = fmaxf(acc[rt][ct][r] + b2c, 0.0f);
                float ef = fast_tanh(fnc + fb + emb * gc + tc);
                A[row][col] = f2b(ef);
            }
        }
    }
    __syncthreads();

    // GEMM2: C2[64][128] = edge_feat @ We1
    floatx4 acc2[4][2];
#pragma unroll
    for (int rt = 0; rt < 4; rt++)
#pragma unroll
        for (int c2 = 0; c2 < 2; c2++) acc2[rt][c2] = (floatx4){0, 0, 0, 0};
#pragma unroll 2
    for (int kt = 0; kt < 8; kt++) {
        shortx8 bf[2];
#pragma unroll
        for (int c2 = 0; c2 < 2; c2++)
            bf[c2] = *(const shortx8*)&we1t[(w * 32 + c2 * 16 + lq) * 256 + kt * 32 + quad * 8];
#pragma unroll
        for (int rt = 0; rt < 4; rt++) {
            shortx8 a = *(const shortx8*)&A[rt * 16 + lq][kt * 32 + quad * 8];
#pragma unroll
            for (int c2 = 0; c2 < 2; c2++)
                acc2[rt][c2] = __builtin_amdgcn_mfma_f32_16x16x32_bf16(a, bf[c2], acc2[rt][c2], 0, 0, 0);
        }
    }

    // logits partials
    float pl[4][4];
#pragma unroll
    for (int rt = 0; rt < 4; rt++)
#pragma unroll
        for (int r = 0; r < 4; r++) pl[rt][r] = 0.0f;
#pragma unroll
    for (int c2 = 0; c2 < 2; c2++) {
        int col = w * 32 + c2 * 16 + lq;
        float be1c = be1[col], w2c = we2[col];
#pragma unroll
        for (int rt = 0; rt < 4; rt++)
#pragma unroll
            for (int r = 0; r < 4; r++)
                pl[rt][r] += fmaxf(acc2[rt][c2][r] + be1c, 0.0f) * w2c;
    }
#pragma unroll
    for (int d = 1; d < 16; d <<= 1)
#pragma unroll
        for (int rt = 0; rt < 4; rt++)
#pragma unroll
            for (int r = 0; r < 4; r++) pl[rt][r] += __shfl_xor(pl[rt][r], d, 16);
    if (lq == 0) {
#pragma unroll
        for (int rt = 0; rt < 4; rt++)
#pragma unroll
            for (int r = 0; r < 4; r++)
                part[w][rt * 16 + quad * 4 + r] = pl[rt][r];
    }
    __syncthreads();
    if (h < 64)
        logitsS[h] = part[0][h] + part[1][h] + part[2][h] + part[3][h] + be2[0];
    __syncthreads();
    if (h < 64) {
        int base = (h >> 4) * 16;
        float mx = -1e30f;
#pragma unroll
        for (int j = 0; j < KNN; j++) mx = fmaxf(mx, logitsS[base + j]);
        float sum = 0.0f;
#pragma unroll
        for (int j = 0; j < KNN; j++) sum += expf(logitsS[base + j] - mx);
        alphaS[h] = expf(logitsS[h] - mx) / sum;
    }
    __syncthreads();

    // ctx: thread -> (point p, 4 cols); bf16 gather over 16 nbrs, bf16 write
    {
        int p = h >> 6, cg = (h & 63) * 4;
        float4 c = {0, 0, 0, 0};
#pragma unroll
        for (int j = 0; j < KNN; j++) {
            float al = alphaS[p * 16 + j];
            const u32* mp = (const u32*)&MSGB[((size_t)b * NPT + nidxS[p * 16 + j]) * H + cg];
            u32 m0 = mp[0], m1 = mp[1];
            c.x += al * __uint_as_float(m0 << 16);
            c.y += al * __uint_as_float(m0 & 0xFFFF0000u);
            c.z += al * __uint_as_float(m1 << 16);
            c.w += al * __uint_as_float(m1 & 0xFFFF0000u);
        }
        uint2 st;
        st.x = (u32)f2b(c.x) | ((u32)f2b(c.y) << 16);
        st.y = (u32)f2b(c.z) | ((u32)f2b(c.w) << 16);
        *(uint2*)&ctxB[(size_t)(bn0 + p) * H + cg] = st;
    }
}

// ---------------------------------------------------------------------------
// K5: out = LN(feat + relu([feat|ctx] @ Wo + bo)), MFMA, 32 points/block.
// A staged directly from featB/ctxB (no cvt); residual keeps f32 feat.
// ---------------------------------------------------------------------------
__global__ __launch_bounds__(256, 4) void out_mfma(const float* __restrict__ feat,
                                                   const u16* __restrict__ featB,
                                                   const u16* __restrict__ ctxB,
                                                   const u16* __restrict__ wot,
                                                   const float* __restrict__ bo,
                                                   const float* __restrict__ gamma,
                                                   const float* __restrict__ beta,
                                                   float* __restrict__ out) {
    __shared__ __attribute__((aligned(16))) u16 A[32][520];
    __shared__ float redS[4][32], redS2[4][32];
    int p0 = blockIdx.x * 32, h = threadIdx.x;
    int w = h >> 6, lane = h & 63, quad = lane >> 4, lq = lane & 15;
#pragma unroll 8
    for (int row = 0; row < 32; row++) {
        A[row][h]       = featB[(size_t)(p0 + row) * H + h];
        A[row][256 + h] = ctxB[(size_t)(p0 + row) * H + h];
    }
    __syncthreads();
    floatx4 acc[2][4];
#pragma unroll
    for (int rt = 0; rt < 2; rt++)
#pragma unroll
        for (int ct = 0; ct < 4; ct++) acc[rt][ct] = (floatx4){0, 0, 0, 0};
#pragma unroll 2
    for (int kt = 0; kt < 16; kt++) {
        shortx8 bf[4];
#pragma unroll
        for (int ct = 0; ct < 4; ct++)
            bf[ct] = *(const shortx8*)&wot[(w * 64 + ct * 16 + lq) * 512 + kt * 32 + quad * 8];
#pragma unroll
        for (int rt = 0; rt < 2; rt++) {
            shortx8 a = *(const shortx8*)&A[rt * 16 + lq][kt * 32 + quad * 8];
#pragma unroll
            for (int ct = 0; ct < 4; ct++)
                acc[rt][ct] = __builtin_amdgcn_mfma_f32_16x16x32_bf16(a, bf[ct], acc[rt][ct], 0, 0, 0);
        }
    }
    float x[2][4][4];
    float sm[2][4], sq2[2][4];
#pragma unroll
    for (int rt = 0; rt < 2; rt++)
#pragma unroll
        for (int r = 0; r < 4; r++) { sm[rt][r] = 0.0f; sq2[rt][r] = 0.0f; }
#pragma unroll
    for (int rt = 0; rt < 2; rt++)
#pragma unroll
        for (int ct = 0; ct < 4; ct++) {
            int col = w * 64 + ct * 16 + lq;
            float boc = bo[col];
#pragma unroll
            for (int r = 0; r < 4; r++) {
                int row = rt * 16 + quad * 4 + r;
                float xx = feat[(size_t)(p0 + row) * H + col] +
                           fmaxf(acc[rt][ct][r] + boc, 0.0f);
                x[rt][ct][r] = xx;
                sm[rt][r] += xx;
                sq2[rt][r] += xx * xx;
            }
        }
#pragma unroll
    for (int d = 1; d < 16; d <<= 1)
#pragma unroll
        for (int rt = 0; rt < 2; rt++)
#pragma unroll
            for (int r = 0; r < 4; r++) {
                sm[rt][r] += __shfl_xor(sm[rt][r], d, 16);
                sq2[rt][r] += __shfl_xor(sq2[rt][r], d, 16);
            }
    if (lq == 0) {
#pragma unroll
        for (int rt = 0; rt < 2; rt++)
#pragma unroll
            for (int r = 0; r < 4; r++) {
                redS[w][rt * 16 + quad * 4 + r] = sm[rt][r];
                redS2[w][rt * 16 + quad * 4 + r] = sq2[rt][r];
            }
    }
    __syncthreads();
#pragma unroll
    for (int rt = 0; rt < 2; rt++)
#pragma unroll
        for (int r = 0; r < 4; r++) {
            int row = rt * 16 + quad * 4 + r;
            float s1 = redS[0][row] + redS[1][row] + redS[2][row] + redS[3][row];
            float s2 = redS2[0][row] + redS2[1][row] + redS2[2][row] + redS2[3][row];
            float mu = s1 * (1.0f / H);
            float var = s2 * (1.0f / H) - mu * mu;
            float inv = rsqrtf(fmaxf(var, 0.0f) + 1e-5f);
#pragma unroll
            for (int ct = 0; ct < 4; ct++) {
                int col = w * 64 + ct * 16 + lq;
                out[(size_t)(p0 + row) * H + col] =
                    (x[rt][ct][r] - mu) * inv * gamma[col] + beta[col];
            }
        }
}

// ---------------------------------------------------------------------------
extern "C" void kernel_launch(void* const* d_in, const int* in_sizes, int n_in,
                              void* d_out, int out_size, void* d_ws, size_t ws_size,
                              hipStream_t stream) {
    const float* feat    = (const float*)d_in[0];
    const float* centers = (const float*)d_in[1];
    const float* textg   = (const float*)d_in[2];
    const float* w1      = (const float*)d_in[3];
    const float* b1      = (const float*)d_in[4];
    const float* w2      = (const float*)d_in[5];
    const float* b2      = (const float*)d_in[6];
    const float* wg      = (const float*)d_in[7];
    const float* bg      = (const float*)d_in[8];
    const float* wtb     = (const float*)d_in[9];
    const float* btb     = (const float*)d_in[10];
    const float* we1     = (const float*)d_in[11];
    const float* be1     = (const float*)d_in[12];
    const float* we2     = (const float*)d_in[13];
    const float* be2     = (const float*)d_in[14];
    const float* wm      = (const float*)d_in[15];
    const float* bm      = (const float*)d_in[16];
    const float* wo      = (const float*)d_in[17];
    const float* bo      = (const float*)d_in[18];
    const float* gamma   = (const float*)d_in[19];
    const float* beta    = (const float*)d_in[20];

    char* ws = (char*)d_ws;
    size_t off = 0;
    int* knn     = (int*)(ws + off);   off += (size_t)BB * NPT * KNN * 4;   // 1 MB
    float* gate  = (float*)(ws + off); off += (size_t)BB * H * 4;           // 64 KB
    float* tbias = (float*)(ws + off); off += (size_t)BB * H * 4;           // 64 KB
    u16* MSGB    = (u16*)(ws + off);   off += (size_t)BB * NPT * H * 2;     // 8 MB
    u16* ctxB    = (u16*)(ws + off);   off += (size_t)BB * NPT * H * 2;     // 8 MB
    u16* featB   = (u16*)(ws + off);   off += (size_t)BB * NPT * H * 2;     // 8 MB
    u16* w2t     = (u16*)(ws + off);   off += (size_t)256 * 256 * 2;        // 128 KB
    u16* we1t    = (u16*)(ws + off);   off += (size_t)128 * 256 * 2;        // 64 KB
    u16* wmt     = (u16*)(ws + off);   off += (size_t)256 * 256 * 2;        // 128 KB
    u16* wot     = (u16*)(ws + off);   off += (size_t)256 * 512 * 2;        // 256 KB
    u16* w1t     = (u16*)(ws + off);   off += (size_t)256 * 32 * 2;         // 16 KB

    prep_kernel<<<5280, 256, 0, stream>>>(feat, w2, we1, wm, wo, w1, b1,
                                          w2t, we1t, wmt, wot, w1t, featB);
    knn_kernel<<<256, 256, 0, stream>>>(centers, knn);
    gate_kernel<<<BB, 512, 0, stream>>>(textg, wg, bg, wtb, btb, gate, tbias);
    msg_mfma<<<BB * NPT / 64, 256, 0, stream>>>(featB, wmt, bm, MSGB);
    edge_mfma<<<BB * NPT / 4, 256, 0, stream>>>(feat, featB, centers, w1t, w2t, b2,
                                                we1t, be1, we2, be2, knn, gate, tbias,
                                                MSGB, ctxB);
    out_mfma<<<BB * NPT / 32, 256, 0, stream>>>(feat, featB, ctxB, wot, bo,
                                                gamma, beta, (float*)d_out);
}